// Round 8
// baseline (256.070 us; speedup 1.0000x reference)
//
#include <hip/hip_runtime.h>

#define BB 4
#define PP 10
#define NN 400000
#define HH 480
#define WW 640
constexpr int HW    = HH * WW;        // 307200
constexpr int NXB   = HW / 256;       // 1200 (focus blocks per image)
constexpr int NXB4  = HW / 1024;      // 300 (flow tiles per plane, 4 px/thread)
constexpr int NTILE = NXB4 * BB * PP; // 12000 flow tiles
constexpr int CHUNK = NTILE / 8;      // 1500 tiles per XCD
constexpr int NSCAT = 1024;           // scatter-role blocks (launched first)
constexpr int EVS   = (BB * NN + NSCAT - 1) / NSCAT;   // 1563 events per scatter block

// quad images: 4 parity images, each [BB][2][240][320] u64 quads
constexpr int QW = WW / 2, QH = HH / 2, QN = QW * QH;
constexpr size_t IMG_QUADS = (size_t)4 * BB * 2 * QN;   // 19.66 MB

constexpr float SCALE     = 1024.0f;
constexpr float INV_SCALE = 1.0f / 1024.0f;

// ---- partial-sum layout (floats) ----
constexpr int PF_V = 0;                          // [BB][1200]        (focus blocks)
constexpr int PF_N = PF_V + BB * NXB;            // 4800
constexpr int PT_D = PF_N + BB * NXB;            // [36][1200]        (tile*4 waves)
constexpr int PT_M = PT_D + BB * (PP-1) * NXB4 * 4;
constexpr int PS   = PT_M + BB * (PP-1) * NXB4 * 4;   // [40][1200]
constexpr int NPART = PS + BB * PP * NXB4 * 4;   // 144000

// ---------- helpers ----------

__device__ __forceinline__ float fsq(float a) { return __builtin_amdgcn_sqrtf(a); }
__device__ __forceinline__ float charb(float a) { return fsq(fmaf(a, a, 1e-6f)); }

// 64-lane wave reduction of three values (no barriers)
__device__ __forceinline__ void waveSum3(float& a, float& b, float& c) {
    #pragma unroll
    for (int off = 32; off > 0; off >>= 1) {
        a += __shfl_down(a, off, 64);
        b += __shfl_down(b, off, 64);
        c += __shfl_down(c, off, 64);
    }
}

__device__ __forceinline__ float blockSum256(float v, float* smem) {
    #pragma unroll
    for (int off = 32; off > 0; off >>= 1)
        v += __shfl_down(v, off, 64);
    int lane = threadIdx.x & 63;
    int wid  = threadIdx.x >> 6;
    if (lane == 0) smem[wid] = v;
    __syncthreads();
    float r = 0.f;
    if (threadIdx.x == 0) r = smem[0] + smem[1] + smem[2] + smem[3];
    __syncthreads();
    return r;
}

__device__ __forceinline__ void scatter_one(int e,
                                            const float2* __restrict__ we,
                                            const float* __restrict__ pol,
                                            const float* __restrict__ tsl,
                                            unsigned long long* __restrict__ img) {
    int b = e / NN;
    int m = e - b * NN;
    float2 c = we[e];
    float y = c.x, x = c.y;
    float pm0 = pol[((size_t)b * 4 * NN + m) * 2];
    float ts  = tsl[(size_t)b * 4 * NN + m];
    float nts = 1.0f - fabsf(1.0f - ts);
    float tyf = fminf(fmaxf(floorf(y), 0.f), (float)(HH - 2));
    float lxf = fminf(fmaxf(floorf(x), 0.f), (float)(WW - 2));
    float fy_ = y - tyf, fx_ = x - lxf;
    float gy = 1.f - fy_, gx = 1.f - fx_;
    float s = nts * SCALE;
    unsigned long long wTL = (unsigned int)(gy * gx * s + 0.5f);
    unsigned long long wTR = (unsigned int)(gy * fx_ * s + 0.5f);
    unsigned long long wBL = (unsigned int)(fy_ * gx * s + 0.5f);
    unsigned long long wBR = (unsigned int)(fy_ * fx_ * s + 0.5f);
    unsigned long long val = wTL | (wTR << 16) | (wBL << 32) | (wBR << 48);
    int ty = (int)tyf, lx = (int)lxf;
    int pi = ((ty & 1) << 1) | (lx & 1);
    int pl = (pm0 > 0.5f) ? 0 : 1;
    size_t wi = ((size_t)((pi * BB + b) * 2 + pl)) * QN + (ty >> 1) * QW + (lx >> 1);
    atomicAdd(&img[wi], val);
}

// ---------- 1. role-split fused kernel: scatter blocks + flow blocks ----------
// Scatter blocks (first NSCAT): pure fire-and-forget atomics, NO barriers ->
// the vmcnt(0) drain happens once at end-of-kernel, fully pipelined.
// Flow blocks: per-wave shuffle reduction only, NO __syncthreads anywhere.

__global__ __launch_bounds__(256)
void fused_kernel(const float2* __restrict__ we,
                  const float* __restrict__ pol,
                  const float* __restrict__ tsl,
                  const float* __restrict__ FX, const float* __restrict__ FY,
                  unsigned long long* __restrict__ img,
                  float* __restrict__ part) {
    int w = blockIdx.x;
    int t = threadIdx.x;

    if (w < NSCAT) {
        // ---- scatter role ----
        int base = w * EVS;
        int cnt  = BB * NN - base;
        if (cnt > EVS) cnt = EVS;
        for (int k = t; k < cnt; k += 256)
            scatter_one(base + k, we, pol, tsl, img);
        return;
    }

    // ---- flow role ----
    int l0 = w - NSCAT;                       // 0..NTILE-1
    int l  = (l0 & 7) * CHUNK + (l0 >> 3);    // XCD-chunked bijection
    int bp = l / NXB4;
    int xb = l - bp * NXB4;
    int b2 = bp / PP;
    int j  = bp - b2 * PP;
    int p0 = xb * 1024 + t * 4;
    int y  = p0 / WW;
    int x0 = p0 - y * WW;                     // multiple of 4 (640%4==0)
    const float* fx = FX + (size_t)bp * HW;
    const float* fy = FY + (size_t)bp * HW;
    float4 vx = *(const float4*)(fx + p0);
    float4 vy = *(const float4*)(fy + p0);
    bool yin  = (y + 1 < HH);
    bool xend = (x0 == WW - 4);
    float4 bx4 = make_float4(0.f, 0.f, 0.f, 0.f), by4 = bx4;
    float vxr = 0.f, vyr = 0.f, bxr = 0.f, byr = 0.f;
    if (yin) {
        bx4 = *(const float4*)(fx + p0 + WW);
        by4 = *(const float4*)(fy + p0 + WW);
    }
    if (!xend) { vxr = fx[p0 + 4]; vyr = fy[p0 + 4]; }
    if (yin && !xend) { bxr = fx[p0 + WW + 4]; byr = fy[p0 + WW + 4]; }

    constexpr float cdx = 1.0f / ((float)HH * (WW - 1) * 4.0f * PP);
    constexpr float cdy = 1.0f / ((float)(HH - 1) * WW * 4.0f * PP);
    constexpr float cdd = 1.0f / ((float)(HH - 1) * (WW - 1) * 4.0f * PP);

    float acc = 0.f;
    acc += (charb(vx.x - vx.y) + charb(vy.x - vy.y)) * cdx;
    acc += (charb(vx.y - vx.z) + charb(vy.y - vy.z)) * cdx;
    acc += (charb(vx.z - vx.w) + charb(vy.z - vy.w)) * cdx;
    if (!xend) acc += (charb(vx.w - vxr) + charb(vy.w - vyr)) * cdx;
    if (yin) {
        acc += (charb(vx.x - bx4.x) + charb(vy.x - by4.x)) * cdy;
        acc += (charb(vx.y - bx4.y) + charb(vy.y - by4.y)) * cdy;
        acc += (charb(vx.z - bx4.z) + charb(vy.z - by4.z)) * cdy;
        acc += (charb(vx.w - bx4.w) + charb(vy.w - by4.w)) * cdy;
        acc += (charb(vx.x - bx4.y) + charb(vy.x - by4.y)) * cdd;
        acc += (charb(vx.y - bx4.z) + charb(vy.y - by4.z)) * cdd;
        acc += (charb(vx.z - bx4.w) + charb(vy.z - by4.w)) * cdd;
        acc += (charb(bx4.x - vx.y) + charb(by4.x - vy.y)) * cdd;
        acc += (charb(bx4.y - vx.z) + charb(by4.y - vy.z)) * cdd;
        acc += (charb(bx4.z - vx.w) + charb(by4.z - vy.w)) * cdd;
        if (!xend) {
            acc += (charb(vx.w - bxr) + charb(vy.w - byr)) * cdd;
            acc += (charb(bx4.w - vxr) + charb(by4.w - vyr)) * cdd;
        }
    }

    float td = 0.f, tm = 0.f;
    if (j < PP - 1) {
        const float* gx1 = fx + HW;
        const float* gy1 = fy + HW;
        float ax[4] = {vx.x, vx.y, vx.z, vx.w};
        float ay[4] = {vy.x, vy.y, vy.z, vy.w};
        #pragma unroll
        for (int i = 0; i < 4; ++i) {
            float ly  = (float)y + ay[i];
            float lx2 = (float)(x0 + i) + ax[i];
            bool m = (ly >= 0.f) && (ly <= (float)(HH - 1)) &&
                     (lx2 >= 0.f) && (lx2 <= (float)(WW - 1));
            if (m) {
                tm += 1.f;
                float tyf = fminf(fmaxf(floorf(ly),  0.f), (float)(HH - 2));
                float txf = fminf(fmaxf(floorf(lx2), 0.f), (float)(WW - 2));
                float fyy = ly - tyf, fxx = lx2 - txf;
                float gyy = 1.f - fyy, gxx = 1.f - fxx;
                int pix = (int)tyf * WW + (int)txf;
                float sx = gyy * (gxx * gx1[pix]      + fxx * gx1[pix + 1]) +
                           fyy * (gxx * gx1[pix + WW] + fxx * gx1[pix + WW + 1]);
                float sy = gyy * (gxx * gy1[pix]      + fxx * gy1[pix + 1]) +
                           fyy * (gxx * gy1[pix + WW] + fxx * gy1[pix + WW + 1]);
                float dy_ = ay[i] - sy;
                float dx_ = ax[i] - sx;
                td += fsq(fmaf(dy_, dy_, 1e-9f)) + fsq(fmaf(dx_, dx_, 1e-9f));
            }
        }
    }

    waveSum3(acc, td, tm);
    if ((t & 63) == 0) {
        int wid = t >> 6;                    // 0..3
        part[PS + (bp * NXB4 + xb) * 4 + wid] = acc;
        if (j < PP - 1) {
            int bj = b2 * (PP - 1) + j;
            part[PT_D + (bj * NXB4 + xb) * 4 + wid] = td;
            part[PT_M + (bj * NXB4 + xb) * 4 + wid] = tm;
        }
    }
}

// ---------- 2. focus reduction -> partials ----------

__global__ __launch_bounds__(256)
void focus_kernel(const unsigned long long* __restrict__ img,
                  float* __restrict__ part) {
    __shared__ float sm[8];
    int b = blockIdx.y;
    int p = blockIdx.x * 256 + threadIdx.x;
    int y = p / WW;
    int x = p - y * WW;
    unsigned int sp = 0, sn = 0;
    #pragma unroll
    for (int dy = 0; dy < 2; ++dy) {
        #pragma unroll
        for (int dx = 0; dx < 2; ++dx) {
            int ty = y - dy, lx = x - dx;
            if (ty < 0 || lx < 0 || ty > HH - 2 || lx > WW - 2) continue;
            int pi = ((ty & 1) << 1) | (lx & 1);
            size_t base = ((size_t)(pi * BB + b) * 2) * QN + (ty >> 1) * QW + (lx >> 1);
            int sh = 16 * ((dy << 1) | dx);
            sp += (unsigned int)((img[base]      >> sh) & 0xFFFFull);
            sn += (unsigned int)((img[base + QN] >> sh) & 0xFFFFull);
        }
    }
    float tp = (float)sp * INV_SCALE;
    float tn = (float)sn * INV_SCALE;
    float v  = tp * tp + tn * tn;
    float nz = ((sp | sn) != 0u) ? 1.f : 0.f;
    float sv  = blockSum256(v, sm);
    float snz = blockSum256(nz, sm + 4);
    if (threadIdx.x == 0) {
        part[PF_V + b * NXB + blockIdx.x] = sv;
        part[PF_N + b * NXB + blockIdx.x] = snz;
    }
}

// ---------- 3. segment reduce ----------

__global__ __launch_bounds__(256)
void reduce_kernel(const float* __restrict__ part, float* __restrict__ seg) {
    __shared__ float sm[4];
    int s = blockIdx.x;                  // 0..80
    int base, len;
    if (s < 4)       { base = PF_V + s * NXB;             len = NXB; }
    else if (s < 8)  { base = PF_N + (s - 4) * NXB;       len = NXB; }
    else if (s < 44) { base = PT_D + (s - 8) * NXB4 * 4;  len = NXB4 * 4; }
    else if (s < 80) { base = PT_M + (s - 44) * NXB4 * 4; len = NXB4 * 4; }
    else             { base = PS;                         len = BB * PP * NXB4 * 4; }
    float v = 0.f;
    for (int i = threadIdx.x; i < len; i += 256) v += part[base + i];
    float r = blockSum256(v, sm);
    if (threadIdx.x == 0) seg[s] = r;
}

// ---------- 4. final combine ----------

__global__ void final_kernel(const float* __restrict__ seg, float* __restrict__ out) {
    if (threadIdx.x == 0 && blockIdx.x == 0) {
        float focus = 0.f;
        #pragma unroll
        for (int b = 0; b < BB; ++b)
            focus += seg[b] / (seg[BB + b] + 1e-9f);
        float temporal = 0.f;
        #pragma unroll
        for (int k = 0; k < BB * (PP - 1); ++k)
            temporal += seg[8 + k] / (seg[44 + k] + 1e-9f);
        temporal *= 1.0f / (float)(PP - 1);
        out[0] = focus + temporal + seg[80];
    }
}

// ---------- launch ----------

extern "C" void kernel_launch(void* const* d_in, const int* in_sizes, int n_in,
                              void* d_out, int out_size, void* d_ws, size_t ws_size,
                              hipStream_t stream) {
    const float2* we  = (const float2*)d_in[0];  // [B,N,2]
    const float*  pol = (const float*)d_in[1];   // [B,4N,2]
    const float*  tsl = (const float*)d_in[2];   // [B,4N,1]
    const float*  FX  = (const float*)d_in[3];   // [B,P,H,W]
    const float*  FY  = (const float*)d_in[4];   // [B,P,H,W]
    float*              seg  = (float*)d_ws;
    unsigned long long* img  = (unsigned long long*)(seg + 256);   // 8B-aligned
    float*              part = (float*)(img + IMG_QUADS);

    hipMemsetAsync(img, 0, IMG_QUADS * sizeof(unsigned long long), stream);

    fused_kernel<<<NSCAT + NTILE, 256, 0, stream>>>(we, pol, tsl, FX, FY, img, part);
    focus_kernel<<<dim3(NXB, BB), 256, 0, stream>>>(img, part);
    reduce_kernel<<<81, 256, 0, stream>>>(part, seg);
    final_kernel<<<1, 64, 0, stream>>>(seg, (float*)d_out);
}

// Round 9
// 182.125 us; speedup vs baseline: 1.4060x; 1.4060x over previous
//
#include <hip/hip_runtime.h>

#define BB 4
#define PP 10
#define NN 400000
#define HH 480
#define WW 640
constexpr int HW    = HH * WW;        // 307200
constexpr int NXB   = HW / 256;       // 1200 (focus blocks per image)
constexpr int NXB4  = HW / 1024;      // 300 (flow tiles per plane)
constexpr int NTILE = NXB4 * BB * PP; // 12000 flow tiles
constexpr int CHUNK = NTILE / 8;      // 1500 tiles per XCD
constexpr int EVB   = (BB * NN + NTILE - 1) / NTILE;   // 134 events per block

// quad images: 4 parity images, each [BB][2][240][320] u64 quads
constexpr int QW = WW / 2, QH = HH / 2, QN = QW * QH;
constexpr size_t IMG_QUADS = (size_t)4 * BB * 2 * QN;   // 19.66 MB

constexpr float SCALE     = 1024.0f;
constexpr float INV_SCALE = 1.0f / 1024.0f;

// ---- partial-sum layout (floats) ----
constexpr int PF_V = 0;                          // [BB][1200]   (focus blocks)
constexpr int PF_N = PF_V + BB * NXB;
constexpr int PT_D = PF_N + BB * NXB;            // [36][300*4]  (per-wave)
constexpr int PT_M = PT_D + BB * (PP-1) * NXB4 * 4;
constexpr int PS   = PT_M + BB * (PP-1) * NXB4 * 4;   // [40][300*4]
constexpr int NPART = PS + BB * PP * NXB4 * 4;

// ---------- helpers ----------

__device__ __forceinline__ float fsq(float a) { return __builtin_amdgcn_sqrtf(a); }
__device__ __forceinline__ float charb(float a) { return fsq(fmaf(a, a, 1e-6f)); }

// 64-lane wave reduction of three values (no barriers)
__device__ __forceinline__ void waveSum3(float& a, float& b, float& c) {
    #pragma unroll
    for (int off = 32; off > 0; off >>= 1) {
        a += __shfl_down(a, off, 64);
        b += __shfl_down(b, off, 64);
        c += __shfl_down(c, off, 64);
    }
}

__device__ __forceinline__ float blockSum256(float v, float* smem) {
    #pragma unroll
    for (int off = 32; off > 0; off >>= 1)
        v += __shfl_down(v, off, 64);
    int lane = threadIdx.x & 63;
    int wid  = threadIdx.x >> 6;
    if (lane == 0) smem[wid] = v;
    __syncthreads();
    float r = 0.f;
    if (threadIdx.x == 0) r = smem[0] + smem[1] + smem[2] + smem[3];
    __syncthreads();
    return r;
}

__device__ __forceinline__ void scatter_one(int e,
                                            const float2* __restrict__ we,
                                            const float* __restrict__ pol,
                                            const float* __restrict__ tsl,
                                            unsigned long long* __restrict__ img) {
    int b = e / NN;
    int m = e - b * NN;
    float2 c = we[e];
    float y = c.x, x = c.y;
    float pm0 = pol[((size_t)b * 4 * NN + m) * 2];
    float ts  = tsl[(size_t)b * 4 * NN + m];
    float nts = 1.0f - fabsf(1.0f - ts);
    float tyf = fminf(fmaxf(floorf(y), 0.f), (float)(HH - 2));
    float lxf = fminf(fmaxf(floorf(x), 0.f), (float)(WW - 2));
    float fy_ = y - tyf, fx_ = x - lxf;
    float gy = 1.f - fy_, gx = 1.f - fx_;
    float s = nts * SCALE;
    unsigned long long wTL = (unsigned int)(gy * gx * s + 0.5f);
    unsigned long long wTR = (unsigned int)(gy * fx_ * s + 0.5f);
    unsigned long long wBL = (unsigned int)(fy_ * gx * s + 0.5f);
    unsigned long long wBR = (unsigned int)(fy_ * fx_ * s + 0.5f);
    unsigned long long val = wTL | (wTR << 16) | (wBL << 32) | (wBR << 48);
    int ty = (int)tyf, lx = (int)lxf;
    int pi = ((ty & 1) << 1) | (lx & 1);
    int pl = (pm0 > 0.5f) ? 0 : 1;
    size_t wi = ((size_t)((pi * BB + b) * 2 + pl)) * QN + (ty >> 1) * QW + (lx >> 1);
    atomicAdd(&img[wi], val);
}

// ---------- 1. fused kernel: per-tile scatter burst + spatial + temporal ----------
// R6 structure (best measured) + lane-consecutive gather geometry + no barriers.

__global__ __launch_bounds__(256)
void fused_kernel(const float2* __restrict__ we,
                  const float* __restrict__ pol,
                  const float* __restrict__ tsl,
                  const float* __restrict__ FX, const float* __restrict__ FY,
                  unsigned long long* __restrict__ img,
                  float* __restrict__ part) {
    int w = blockIdx.x;
    int t = threadIdx.x;

    // --- scatter burst: one event per thread (EVB=134 < 256), fire-and-forget ---
    int e = w * EVB + t;
    if (t < EVB && e < BB * NN)
        scatter_one(e, we, pol, tsl, img);

    // --- tile decode (XCD-chunked bijection) ---
    int l  = (w & 7) * CHUNK + (w >> 3);
    int bp = l / NXB4;
    int xb = l - bp * NXB4;
    int b2 = bp / PP;
    int j  = bp - b2 * PP;
    const float* fx = FX + (size_t)bp * HW;
    const float* fy = FY + (size_t)bp * HW;

    // ---- spatial phase: 4 consecutive px/thread, float4 loads ----
    int p0 = xb * 1024 + t * 4;
    int y  = p0 / WW;
    int x0 = p0 - y * WW;                 // multiple of 4 (640%4==0)
    float4 vx = *(const float4*)(fx + p0);
    float4 vy = *(const float4*)(fy + p0);
    bool yin  = (y + 1 < HH);
    bool xend = (x0 == WW - 4);
    float4 bx4 = make_float4(0.f, 0.f, 0.f, 0.f), by4 = bx4;
    float vxr = 0.f, vyr = 0.f, bxr = 0.f, byr = 0.f;
    if (yin) {
        bx4 = *(const float4*)(fx + p0 + WW);
        by4 = *(const float4*)(fy + p0 + WW);
    }
    if (!xend) { vxr = fx[p0 + 4]; vyr = fy[p0 + 4]; }
    if (yin && !xend) { bxr = fx[p0 + WW + 4]; byr = fy[p0 + WW + 4]; }

    constexpr float cdx = 1.0f / ((float)HH * (WW - 1) * 4.0f * PP);
    constexpr float cdy = 1.0f / ((float)(HH - 1) * WW * 4.0f * PP);
    constexpr float cdd = 1.0f / ((float)(HH - 1) * (WW - 1) * 4.0f * PP);

    float acc = 0.f;
    acc += (charb(vx.x - vx.y) + charb(vy.x - vy.y)) * cdx;
    acc += (charb(vx.y - vx.z) + charb(vy.y - vy.z)) * cdx;
    acc += (charb(vx.z - vx.w) + charb(vy.z - vy.w)) * cdx;
    if (!xend) acc += (charb(vx.w - vxr) + charb(vy.w - vyr)) * cdx;
    if (yin) {
        acc += (charb(vx.x - bx4.x) + charb(vy.x - by4.x)) * cdy;
        acc += (charb(vx.y - bx4.y) + charb(vy.y - by4.y)) * cdy;
        acc += (charb(vx.z - bx4.z) + charb(vy.z - by4.z)) * cdy;
        acc += (charb(vx.w - bx4.w) + charb(vy.w - by4.w)) * cdy;
        acc += (charb(vx.x - bx4.y) + charb(vy.x - by4.y)) * cdd;
        acc += (charb(vx.y - bx4.z) + charb(vy.y - by4.z)) * cdd;
        acc += (charb(vx.z - bx4.w) + charb(vy.z - by4.w)) * cdd;
        acc += (charb(bx4.x - vx.y) + charb(by4.x - vy.y)) * cdd;
        acc += (charb(bx4.y - vx.z) + charb(by4.y - vy.z)) * cdd;
        acc += (charb(bx4.z - vx.w) + charb(by4.z - vy.w)) * cdd;
        if (!xend) {
            acc += (charb(vx.w - bxr) + charb(vy.w - byr)) * cdd;
            acc += (charb(bx4.w - vxr) + charb(by4.w - vyr)) * cdd;
        }
    }

    // ---- temporal phase: lane-consecutive pixels (stride-256 per thread) ----
    // Consecutive lanes gather from consecutive pixels -> ~4x fewer distinct
    // 64B segments per gather instruction than the 4-consecutive-px layout.
    float td = 0.f, tm = 0.f;
    if (j < PP - 1) {
        const float* gx1 = fx + HW;
        const float* gy1 = fy + HW;
        #pragma unroll
        for (int k = 0; k < 4; ++k) {
            int p  = xb * 1024 + k * 256 + t;
            int yy = p / WW;
            int xx = p - yy * WW;
            float fx00 = fx[p];              // coalesced, L1-hot (spatial just read it)
            float fy00 = fy[p];
            float ly  = (float)yy + fy00;
            float lx2 = (float)xx + fx00;
            bool m = (ly >= 0.f) && (ly <= (float)(HH - 1)) &&
                     (lx2 >= 0.f) && (lx2 <= (float)(WW - 1));
            if (m) {
                tm += 1.f;
                float tyf = fminf(fmaxf(floorf(ly),  0.f), (float)(HH - 2));
                float txf = fminf(fmaxf(floorf(lx2), 0.f), (float)(WW - 2));
                float fyy = ly - tyf, fxx = lx2 - txf;
                float gyy = 1.f - fyy, gxx = 1.f - fxx;
                int pix = (int)tyf * WW + (int)txf;
                float sx = gyy * (gxx * gx1[pix]      + fxx * gx1[pix + 1]) +
                           fyy * (gxx * gx1[pix + WW] + fxx * gx1[pix + WW + 1]);
                float sy = gyy * (gxx * gy1[pix]      + fxx * gy1[pix + 1]) +
                           fyy * (gxx * gy1[pix + WW] + fxx * gy1[pix + WW + 1]);
                float dy_ = fy00 - sy;
                float dx_ = fx00 - sx;
                td += fsq(fmaf(dy_, dy_, 1e-9f)) + fsq(fmaf(dx_, dx_, 1e-9f));
            }
        }
    }

    waveSum3(acc, td, tm);
    if ((t & 63) == 0) {
        int wid = t >> 6;                    // 0..3
        part[PS + (bp * NXB4 + xb) * 4 + wid] = acc;
        if (j < PP - 1) {
            int bj = b2 * (PP - 1) + j;
            part[PT_D + (bj * NXB4 + xb) * 4 + wid] = td;
            part[PT_M + (bj * NXB4 + xb) * 4 + wid] = tm;
        }
    }
}

// ---------- 2. focus reduction -> partials ----------

__global__ __launch_bounds__(256)
void focus_kernel(const unsigned long long* __restrict__ img,
                  float* __restrict__ part) {
    __shared__ float sm[8];
    int b = blockIdx.y;
    int p = blockIdx.x * 256 + threadIdx.x;
    int y = p / WW;
    int x = p - y * WW;
    unsigned int sp = 0, sn = 0;
    #pragma unroll
    for (int dy = 0; dy < 2; ++dy) {
        #pragma unroll
        for (int dx = 0; dx < 2; ++dx) {
            int ty = y - dy, lx = x - dx;
            if (ty < 0 || lx < 0 || ty > HH - 2 || lx > WW - 2) continue;
            int pi = ((ty & 1) << 1) | (lx & 1);
            size_t base = ((size_t)(pi * BB + b) * 2) * QN + (ty >> 1) * QW + (lx >> 1);
            int sh = 16 * ((dy << 1) | dx);
            sp += (unsigned int)((img[base]      >> sh) & 0xFFFFull);
            sn += (unsigned int)((img[base + QN] >> sh) & 0xFFFFull);
        }
    }
    float tp = (float)sp * INV_SCALE;
    float tn = (float)sn * INV_SCALE;
    float v  = tp * tp + tn * tn;
    float nz = ((sp | sn) != 0u) ? 1.f : 0.f;
    float sv  = blockSum256(v, sm);
    float snz = blockSum256(nz, sm + 4);
    if (threadIdx.x == 0) {
        part[PF_V + b * NXB + blockIdx.x] = sv;
        part[PF_N + b * NXB + blockIdx.x] = snz;
    }
}

// ---------- 3. segment reduce ----------

__global__ __launch_bounds__(256)
void reduce_kernel(const float* __restrict__ part, float* __restrict__ seg) {
    __shared__ float sm[4];
    int s = blockIdx.x;                  // 0..80
    int base, len;
    if (s < 4)       { base = PF_V + s * NXB;             len = NXB; }
    else if (s < 8)  { base = PF_N + (s - 4) * NXB;       len = NXB; }
    else if (s < 44) { base = PT_D + (s - 8) * NXB4 * 4;  len = NXB4 * 4; }
    else if (s < 80) { base = PT_M + (s - 44) * NXB4 * 4; len = NXB4 * 4; }
    else             { base = PS;                         len = BB * PP * NXB4 * 4; }
    float v = 0.f;
    for (int i = threadIdx.x; i < len; i += 256) v += part[base + i];
    float r = blockSum256(v, sm);
    if (threadIdx.x == 0) seg[s] = r;
}

// ---------- 4. final combine ----------

__global__ void final_kernel(const float* __restrict__ seg, float* __restrict__ out) {
    if (threadIdx.x == 0 && blockIdx.x == 0) {
        float focus = 0.f;
        #pragma unroll
        for (int b = 0; b < BB; ++b)
            focus += seg[b] / (seg[BB + b] + 1e-9f);
        float temporal = 0.f;
        #pragma unroll
        for (int k = 0; k < BB * (PP - 1); ++k)
            temporal += seg[8 + k] / (seg[44 + k] + 1e-9f);
        temporal *= 1.0f / (float)(PP - 1);
        out[0] = focus + temporal + seg[80];
    }
}

// ---------- launch ----------

extern "C" void kernel_launch(void* const* d_in, const int* in_sizes, int n_in,
                              void* d_out, int out_size, void* d_ws, size_t ws_size,
                              hipStream_t stream) {
    const float2* we  = (const float2*)d_in[0];  // [B,N,2]
    const float*  pol = (const float*)d_in[1];   // [B,4N,2]
    const float*  tsl = (const float*)d_in[2];   // [B,4N,1]
    const float*  FX  = (const float*)d_in[3];   // [B,P,H,W]
    const float*  FY  = (const float*)d_in[4];   // [B,P,H,W]
    float*              seg  = (float*)d_ws;
    unsigned long long* img  = (unsigned long long*)(seg + 256);   // 8B-aligned
    float*              part = (float*)(img + IMG_QUADS);

    hipMemsetAsync(img, 0, IMG_QUADS * sizeof(unsigned long long), stream);

    fused_kernel<<<NTILE, 256, 0, stream>>>(we, pol, tsl, FX, FY, img, part);
    focus_kernel<<<dim3(NXB, BB), 256, 0, stream>>>(img, part);
    reduce_kernel<<<81, 256, 0, stream>>>(part, seg);
    final_kernel<<<1, 64, 0, stream>>>(seg, (float*)d_out);
}

// Round 10
// 181.989 us; speedup vs baseline: 1.4071x; 1.0007x over previous
//
#include <hip/hip_runtime.h>

#define BB 4
#define PP 10
#define NN 400000
#define HH 480
#define WW 640
constexpr int HW    = HH * WW;        // 307200
constexpr int NXB   = HW / 256;       // 1200 (focus blocks per image)
constexpr int NXB4  = HW / 1024;      // 300 (flow tiles per plane)
constexpr int NTILE = NXB4 * BB * PP; // 12000 flow tiles
constexpr int CHUNK = NTILE / 8;      // 1500 tiles per XCD
constexpr int EVB   = (BB * NN + NTILE - 1) / NTILE;   // 134 events per block

// quad images: 4 parity images, each [BB][2][240][320] u64 quads
constexpr int QW = WW / 2, QH = HH / 2, QN = QW * QH;
constexpr size_t IMG_QUADS = (size_t)4 * BB * 2 * QN;   // 19.66 MB

constexpr float SCALE     = 1024.0f;
constexpr float INV_SCALE = 1.0f / 1024.0f;

// ---- partial-sum layout (floats) ----
constexpr int PF_V = 0;                          // [BB][1200]   (focus blocks)
constexpr int PF_N = PF_V + BB * NXB;
constexpr int PT_D = PF_N + BB * NXB;            // [36][300*4]  (per-wave)
constexpr int PT_M = PT_D + BB * (PP-1) * NXB4 * 4;
constexpr int PS   = PT_M + BB * (PP-1) * NXB4 * 4;   // [40][300*4]
constexpr int NPART = PS + BB * PP * NXB4 * 4;

// ---------- helpers ----------

__device__ __forceinline__ float fsq(float a) { return __builtin_amdgcn_sqrtf(a); }
__device__ __forceinline__ float charb(float a) { return fsq(fmaf(a, a, 1e-6f)); }

// 64-lane wave reduction of three values (no barriers)
__device__ __forceinline__ void waveSum3(float& a, float& b, float& c) {
    #pragma unroll
    for (int off = 32; off > 0; off >>= 1) {
        a += __shfl_down(a, off, 64);
        b += __shfl_down(b, off, 64);
        c += __shfl_down(c, off, 64);
    }
}

__device__ __forceinline__ float blockSum256(float v, float* smem) {
    #pragma unroll
    for (int off = 32; off > 0; off >>= 1)
        v += __shfl_down(v, off, 64);
    int lane = threadIdx.x & 63;
    int wid  = threadIdx.x >> 6;
    if (lane == 0) smem[wid] = v;
    __syncthreads();
    float r = 0.f;
    if (threadIdx.x == 0) r = smem[0] + smem[1] + smem[2] + smem[3];
    __syncthreads();
    return r;
}

__device__ __forceinline__ void scatter_one(int e,
                                            const float2* __restrict__ we,
                                            const float* __restrict__ pol,
                                            const float* __restrict__ tsl,
                                            unsigned long long* __restrict__ img) {
    int b = e / NN;
    int m = e - b * NN;
    float2 c = we[e];
    float y = c.x, x = c.y;
    float pm0 = pol[((size_t)b * 4 * NN + m) * 2];
    float ts  = tsl[(size_t)b * 4 * NN + m];
    float nts = 1.0f - fabsf(1.0f - ts);
    float tyf = fminf(fmaxf(floorf(y), 0.f), (float)(HH - 2));
    float lxf = fminf(fmaxf(floorf(x), 0.f), (float)(WW - 2));
    float fy_ = y - tyf, fx_ = x - lxf;
    float gy = 1.f - fy_, gx = 1.f - fx_;
    float s = nts * SCALE;
    unsigned long long wTL = (unsigned int)(gy * gx * s + 0.5f);
    unsigned long long wTR = (unsigned int)(gy * fx_ * s + 0.5f);
    unsigned long long wBL = (unsigned int)(fy_ * gx * s + 0.5f);
    unsigned long long wBR = (unsigned int)(fy_ * fx_ * s + 0.5f);
    unsigned long long val = wTL | (wTR << 16) | (wBL << 32) | (wBR << 48);
    int ty = (int)tyf, lx = (int)lxf;
    int pi = ((ty & 1) << 1) | (lx & 1);
    int pl = (pm0 > 0.5f) ? 0 : 1;
    size_t wi = ((size_t)((pi * BB + b) * 2 + pl)) * QN + (ty >> 1) * QW + (lx >> 1);
    atomicAdd(&img[wi], val);
}

// ---------- 1. fused kernel: flow first, scatter atomics issued LAST ----------
// vmcnt completes in issue order: an atomic issued before the flow loads makes
// every flow s_waitcnt drain the (saturated) atomic queue first. Issuing the
// atomic after the last waited load decouples flow compute from atomic latency.

__global__ __launch_bounds__(256)
void fused_kernel(const float2* __restrict__ we,
                  const float* __restrict__ pol,
                  const float* __restrict__ tsl,
                  const float* __restrict__ FX, const float* __restrict__ FY,
                  unsigned long long* __restrict__ img,
                  float* __restrict__ part) {
    int w = blockIdx.x;
    int t = threadIdx.x;

    // --- tile decode (XCD-chunked bijection) ---
    int l  = (w & 7) * CHUNK + (w >> 3);
    int bp = l / NXB4;
    int xb = l - bp * NXB4;
    int b2 = bp / PP;
    int j  = bp - b2 * PP;
    const float* fx = FX + (size_t)bp * HW;
    const float* fy = FY + (size_t)bp * HW;

    // ---- spatial phase: 4 consecutive px/thread, float4 loads ----
    int p0 = xb * 1024 + t * 4;
    int y  = p0 / WW;
    int x0 = p0 - y * WW;                 // multiple of 4 (640%4==0)
    float4 vx = *(const float4*)(fx + p0);
    float4 vy = *(const float4*)(fy + p0);
    bool yin  = (y + 1 < HH);
    bool xend = (x0 == WW - 4);
    float4 bx4 = make_float4(0.f, 0.f, 0.f, 0.f), by4 = bx4;
    float vxr = 0.f, vyr = 0.f, bxr = 0.f, byr = 0.f;
    if (yin) {
        bx4 = *(const float4*)(fx + p0 + WW);
        by4 = *(const float4*)(fy + p0 + WW);
    }
    if (!xend) { vxr = fx[p0 + 4]; vyr = fy[p0 + 4]; }
    if (yin && !xend) { bxr = fx[p0 + WW + 4]; byr = fy[p0 + WW + 4]; }

    constexpr float cdx = 1.0f / ((float)HH * (WW - 1) * 4.0f * PP);
    constexpr float cdy = 1.0f / ((float)(HH - 1) * WW * 4.0f * PP);
    constexpr float cdd = 1.0f / ((float)(HH - 1) * (WW - 1) * 4.0f * PP);

    float acc = 0.f;
    acc += (charb(vx.x - vx.y) + charb(vy.x - vy.y)) * cdx;
    acc += (charb(vx.y - vx.z) + charb(vy.y - vy.z)) * cdx;
    acc += (charb(vx.z - vx.w) + charb(vy.z - vy.w)) * cdx;
    if (!xend) acc += (charb(vx.w - vxr) + charb(vy.w - vyr)) * cdx;
    if (yin) {
        acc += (charb(vx.x - bx4.x) + charb(vy.x - by4.x)) * cdy;
        acc += (charb(vx.y - bx4.y) + charb(vy.y - by4.y)) * cdy;
        acc += (charb(vx.z - bx4.z) + charb(vy.z - by4.z)) * cdy;
        acc += (charb(vx.w - bx4.w) + charb(vy.w - by4.w)) * cdy;
        acc += (charb(vx.x - bx4.y) + charb(vy.x - by4.y)) * cdd;
        acc += (charb(vx.y - bx4.z) + charb(vy.y - by4.z)) * cdd;
        acc += (charb(vx.z - bx4.w) + charb(vy.z - by4.w)) * cdd;
        acc += (charb(bx4.x - vx.y) + charb(by4.x - vy.y)) * cdd;
        acc += (charb(bx4.y - vx.z) + charb(by4.y - vy.z)) * cdd;
        acc += (charb(bx4.z - vx.w) + charb(by4.z - vy.w)) * cdd;
        if (!xend) {
            acc += (charb(vx.w - bxr) + charb(vy.w - byr)) * cdd;
            acc += (charb(bx4.w - vxr) + charb(by4.w - vyr)) * cdd;
        }
    }

    // ---- temporal phase: lane-consecutive pixels (stride-256 per thread) ----
    float td = 0.f, tm = 0.f;
    if (j < PP - 1) {
        const float* gx1 = fx + HW;
        const float* gy1 = fy + HW;
        #pragma unroll
        for (int k = 0; k < 4; ++k) {
            int p  = xb * 1024 + k * 256 + t;
            int yy = p / WW;
            int xx = p - yy * WW;
            float fx00 = fx[p];              // coalesced, L1-hot
            float fy00 = fy[p];
            float ly  = (float)yy + fy00;
            float lx2 = (float)xx + fx00;
            bool m = (ly >= 0.f) && (ly <= (float)(HH - 1)) &&
                     (lx2 >= 0.f) && (lx2 <= (float)(WW - 1));
            if (m) {
                tm += 1.f;
                float tyf = fminf(fmaxf(floorf(ly),  0.f), (float)(HH - 2));
                float txf = fminf(fmaxf(floorf(lx2), 0.f), (float)(WW - 2));
                float fyy = ly - tyf, fxx = lx2 - txf;
                float gyy = 1.f - fyy, gxx = 1.f - fxx;
                int pix = (int)tyf * WW + (int)txf;
                float sx = gyy * (gxx * gx1[pix]      + fxx * gx1[pix + 1]) +
                           fyy * (gxx * gx1[pix + WW] + fxx * gx1[pix + WW + 1]);
                float sy = gyy * (gxx * gy1[pix]      + fxx * gy1[pix + 1]) +
                           fyy * (gxx * gy1[pix + WW] + fxx * gy1[pix + WW + 1]);
                float dy_ = fy00 - sy;
                float dx_ = fx00 - sx;
                td += fsq(fmaf(dy_, dy_, 1e-9f)) + fsq(fmaf(dx_, dx_, 1e-9f));
            }
        }
    }

    // ---- scatter burst LAST: no vmcnt wait after the atomic ----
    __builtin_amdgcn_sched_barrier(0);       // pin atomic issue after flow loads
    int e = w * EVB + t;
    if (t < EVB && e < BB * NN)
        scatter_one(e, we, pol, tsl, img);
    __builtin_amdgcn_sched_barrier(0);

    waveSum3(acc, td, tm);
    if ((t & 63) == 0) {
        int wid = t >> 6;                    // 0..3
        part[PS + (bp * NXB4 + xb) * 4 + wid] = acc;
        if (j < PP - 1) {
            int bj = b2 * (PP - 1) + j;
            part[PT_D + (bj * NXB4 + xb) * 4 + wid] = td;
            part[PT_M + (bj * NXB4 + xb) * 4 + wid] = tm;
        }
    }
}

// ---------- 2. focus reduction -> partials ----------

__global__ __launch_bounds__(256)
void focus_kernel(const unsigned long long* __restrict__ img,
                  float* __restrict__ part) {
    __shared__ float sm[8];
    int b = blockIdx.y;
    int p = blockIdx.x * 256 + threadIdx.x;
    int y = p / WW;
    int x = p - y * WW;
    unsigned int sp = 0, sn = 0;
    #pragma unroll
    for (int dy = 0; dy < 2; ++dy) {
        #pragma unroll
        for (int dx = 0; dx < 2; ++dx) {
            int ty = y - dy, lx = x - dx;
            if (ty < 0 || lx < 0 || ty > HH - 2 || lx > WW - 2) continue;
            int pi = ((ty & 1) << 1) | (lx & 1);
            size_t base = ((size_t)(pi * BB + b) * 2) * QN + (ty >> 1) * QW + (lx >> 1);
            int sh = 16 * ((dy << 1) | dx);
            sp += (unsigned int)((img[base]      >> sh) & 0xFFFFull);
            sn += (unsigned int)((img[base + QN] >> sh) & 0xFFFFull);
        }
    }
    float tp = (float)sp * INV_SCALE;
    float tn = (float)sn * INV_SCALE;
    float v  = tp * tp + tn * tn;
    float nz = ((sp | sn) != 0u) ? 1.f : 0.f;
    float sv  = blockSum256(v, sm);
    float snz = blockSum256(nz, sm + 4);
    if (threadIdx.x == 0) {
        part[PF_V + b * NXB + blockIdx.x] = sv;
        part[PF_N + b * NXB + blockIdx.x] = snz;
    }
}

// ---------- 3. segment reduce ----------

__global__ __launch_bounds__(256)
void reduce_kernel(const float* __restrict__ part, float* __restrict__ seg) {
    __shared__ float sm[4];
    int s = blockIdx.x;                  // 0..80
    int base, len;
    if (s < 4)       { base = PF_V + s * NXB;             len = NXB; }
    else if (s < 8)  { base = PF_N + (s - 4) * NXB;       len = NXB; }
    else if (s < 44) { base = PT_D + (s - 8) * NXB4 * 4;  len = NXB4 * 4; }
    else if (s < 80) { base = PT_M + (s - 44) * NXB4 * 4; len = NXB4 * 4; }
    else             { base = PS;                         len = BB * PP * NXB4 * 4; }
    float v = 0.f;
    for (int i = threadIdx.x; i < len; i += 256) v += part[base + i];
    float r = blockSum256(v, sm);
    if (threadIdx.x == 0) seg[s] = r;
}

// ---------- 4. final combine ----------

__global__ void final_kernel(const float* __restrict__ seg, float* __restrict__ out) {
    if (threadIdx.x == 0 && blockIdx.x == 0) {
        float focus = 0.f;
        #pragma unroll
        for (int b = 0; b < BB; ++b)
            focus += seg[b] / (seg[BB + b] + 1e-9f);
        float temporal = 0.f;
        #pragma unroll
        for (int k = 0; k < BB * (PP - 1); ++k)
            temporal += seg[8 + k] / (seg[44 + k] + 1e-9f);
        temporal *= 1.0f / (float)(PP - 1);
        out[0] = focus + temporal + seg[80];
    }
}

// ---------- launch ----------

extern "C" void kernel_launch(void* const* d_in, const int* in_sizes, int n_in,
                              void* d_out, int out_size, void* d_ws, size_t ws_size,
                              hipStream_t stream) {
    const float2* we  = (const float2*)d_in[0];  // [B,N,2]
    const float*  pol = (const float*)d_in[1];   // [B,4N,2]
    const float*  tsl = (const float*)d_in[2];   // [B,4N,1]
    const float*  FX  = (const float*)d_in[3];   // [B,P,H,W]
    const float*  FY  = (const float*)d_in[4];   // [B,P,H,W]
    float*              seg  = (float*)d_ws;
    unsigned long long* img  = (unsigned long long*)(seg + 256);   // 8B-aligned
    float*              part = (float*)(img + IMG_QUADS);

    hipMemsetAsync(img, 0, IMG_QUADS * sizeof(unsigned long long), stream);

    fused_kernel<<<NTILE, 256, 0, stream>>>(we, pol, tsl, FX, FY, img, part);
    focus_kernel<<<dim3(NXB, BB), 256, 0, stream>>>(img, part);
    reduce_kernel<<<81, 256, 0, stream>>>(part, seg);
    final_kernel<<<1, 64, 0, stream>>>(seg, (float*)d_out);
}

// Round 11
// 180.633 us; speedup vs baseline: 1.4176x; 1.0075x over previous
//
#include <hip/hip_runtime.h>

#define BB 4
#define PP 10
#define NN 400000
#define HH 480
#define WW 640
constexpr int HW    = HH * WW;        // 307200
constexpr int NXB   = HW / 256;       // 1200 (focus blocks per image)
constexpr int NXB4  = HW / 1024;      // 300 (flow tiles per plane)
constexpr int NTILE = NXB4 * BB * PP; // 12000 flow tiles
constexpr int CHUNK = NTILE / 8;      // 1500 tiles per XCD
constexpr int EVB   = (BB * NN + NTILE - 1) / NTILE;   // 134 events per block

// quad images: 4 parity images, each [BB][2][240][320] u64 quads
constexpr int QW = WW / 2, QH = HH / 2, QN = QW * QH;
constexpr size_t IMG_QUADS = (size_t)4 * BB * 2 * QN;   // 19.66 MB

constexpr float SCALE     = 1024.0f;
constexpr float INV_SCALE = 1.0f / 1024.0f;

// ---- partial-sum layout (floats) ----
constexpr int PF_V = 0;                          // [BB][1200]   (focus blocks)
constexpr int PF_N = PF_V + BB * NXB;
constexpr int PT_D = PF_N + BB * NXB;            // [36][300*4]  (per-wave)
constexpr int PT_M = PT_D + BB * (PP-1) * NXB4 * 4;
constexpr int PS   = PT_M + BB * (PP-1) * NXB4 * 4;   // [40][300*4]
constexpr int NPART = PS + BB * PP * NXB4 * 4;

// ---------- helpers ----------

__device__ __forceinline__ float fsq(float a) { return __builtin_amdgcn_sqrtf(a); }
__device__ __forceinline__ float charb(float a) { return fsq(fmaf(a, a, 1e-6f)); }

// 64-lane wave reduction of three values (no barriers)
__device__ __forceinline__ void waveSum3(float& a, float& b, float& c) {
    #pragma unroll
    for (int off = 32; off > 0; off >>= 1) {
        a += __shfl_down(a, off, 64);
        b += __shfl_down(b, off, 64);
        c += __shfl_down(c, off, 64);
    }
}

__device__ __forceinline__ float blockSum256(float v, float* smem) {
    #pragma unroll
    for (int off = 32; off > 0; off >>= 1)
        v += __shfl_down(v, off, 64);
    int lane = threadIdx.x & 63;
    int wid  = threadIdx.x >> 6;
    if (lane == 0) smem[wid] = v;
    __syncthreads();
    float r = 0.f;
    if (threadIdx.x == 0) r = smem[0] + smem[1] + smem[2] + smem[3];
    __syncthreads();
    return r;
}

__device__ __forceinline__ void scatter_one(int e,
                                            const float2* __restrict__ we,
                                            const float* __restrict__ pol,
                                            const float* __restrict__ tsl,
                                            unsigned long long* __restrict__ img) {
    int b = e / NN;
    int m = e - b * NN;
    float2 c = we[e];
    float y = c.x, x = c.y;
    float pm0 = pol[((size_t)b * 4 * NN + m) * 2];
    float ts  = tsl[(size_t)b * 4 * NN + m];
    float nts = 1.0f - fabsf(1.0f - ts);
    float tyf = fminf(fmaxf(floorf(y), 0.f), (float)(HH - 2));
    float lxf = fminf(fmaxf(floorf(x), 0.f), (float)(WW - 2));
    float fy_ = y - tyf, fx_ = x - lxf;
    float gy = 1.f - fy_, gx = 1.f - fx_;
    float s = nts * SCALE;
    unsigned long long wTL = (unsigned int)(gy * gx * s + 0.5f);
    unsigned long long wTR = (unsigned int)(gy * fx_ * s + 0.5f);
    unsigned long long wBL = (unsigned int)(fy_ * gx * s + 0.5f);
    unsigned long long wBR = (unsigned int)(fy_ * fx_ * s + 0.5f);
    unsigned long long val = wTL | (wTR << 16) | (wBL << 32) | (wBR << 48);
    int ty = (int)tyf, lx = (int)lxf;
    int pi = ((ty & 1) << 1) | (lx & 1);
    int pl = (pm0 > 0.5f) ? 0 : 1;
    size_t wi = ((size_t)((pi * BB + b) * 2 + pl)) * QN + (ty >> 1) * QW + (lx >> 1);
    atomicAdd(&img[wi], val);
}

// ---------- 1. fused kernel ----------
// Temporal center values come from __shfl of the spatial registers (same wave)
// instead of reloading fx[p]/fy[p]: the 4 k-iterations become independent, so
// all 32 gather loads can be in flight at once (1 latency exposure, not 8).

__global__ __launch_bounds__(256)
void fused_kernel(const float2* __restrict__ we,
                  const float* __restrict__ pol,
                  const float* __restrict__ tsl,
                  const float* __restrict__ FX, const float* __restrict__ FY,
                  unsigned long long* __restrict__ img,
                  float* __restrict__ part) {
    int w = blockIdx.x;
    int t = threadIdx.x;

    // --- tile decode (XCD-chunked bijection) ---
    int l  = (w & 7) * CHUNK + (w >> 3);
    int bp = l / NXB4;
    int xb = l - bp * NXB4;
    int b2 = bp / PP;
    int j  = bp - b2 * PP;
    const float* fx = FX + (size_t)bp * HW;
    const float* fy = FY + (size_t)bp * HW;

    // ---- spatial phase: 4 consecutive px/thread, float4 loads ----
    int p0 = xb * 1024 + t * 4;
    int y  = p0 / WW;
    int x0 = p0 - y * WW;                 // multiple of 4 (640%4==0)
    float4 vx = *(const float4*)(fx + p0);
    float4 vy = *(const float4*)(fy + p0);
    bool yin  = (y + 1 < HH);
    bool xend = (x0 == WW - 4);
    float4 bx4 = make_float4(0.f, 0.f, 0.f, 0.f), by4 = bx4;
    float vxr = 0.f, vyr = 0.f, bxr = 0.f, byr = 0.f;
    if (yin) {
        bx4 = *(const float4*)(fx + p0 + WW);
        by4 = *(const float4*)(fy + p0 + WW);
    }
    if (!xend) { vxr = fx[p0 + 4]; vyr = fy[p0 + 4]; }
    if (yin && !xend) { bxr = fx[p0 + WW + 4]; byr = fy[p0 + WW + 4]; }

    constexpr float cdx = 1.0f / ((float)HH * (WW - 1) * 4.0f * PP);
    constexpr float cdy = 1.0f / ((float)(HH - 1) * WW * 4.0f * PP);
    constexpr float cdd = 1.0f / ((float)(HH - 1) * (WW - 1) * 4.0f * PP);

    float acc = 0.f;
    acc += (charb(vx.x - vx.y) + charb(vy.x - vy.y)) * cdx;
    acc += (charb(vx.y - vx.z) + charb(vy.y - vy.z)) * cdx;
    acc += (charb(vx.z - vx.w) + charb(vy.z - vy.w)) * cdx;
    if (!xend) acc += (charb(vx.w - vxr) + charb(vy.w - vyr)) * cdx;
    if (yin) {
        acc += (charb(vx.x - bx4.x) + charb(vy.x - by4.x)) * cdy;
        acc += (charb(vx.y - bx4.y) + charb(vy.y - by4.y)) * cdy;
        acc += (charb(vx.z - bx4.z) + charb(vy.z - by4.z)) * cdy;
        acc += (charb(vx.w - bx4.w) + charb(vy.w - by4.w)) * cdy;
        acc += (charb(vx.x - bx4.y) + charb(vy.x - by4.y)) * cdd;
        acc += (charb(vx.y - bx4.z) + charb(vy.y - by4.z)) * cdd;
        acc += (charb(vx.z - bx4.w) + charb(vy.z - by4.w)) * cdd;
        acc += (charb(bx4.x - vx.y) + charb(by4.x - vy.y)) * cdd;
        acc += (charb(bx4.y - vx.z) + charb(by4.y - vy.z)) * cdd;
        acc += (charb(bx4.z - vx.w) + charb(by4.z - vy.w)) * cdd;
        if (!xend) {
            acc += (charb(vx.w - bxr) + charb(vy.w - byr)) * cdd;
            acc += (charb(bx4.w - vxr) + charb(by4.w - vyr)) * cdd;
        }
    }

    // ---- temporal phase: lane-consecutive px, centers via __shfl (no loads) ----
    float td = 0.f, tm = 0.f;
    if (j < PP - 1) {
        const float* gx1 = fx + HW;
        const float* gy1 = fy + HW;
        int wv    = t >> 6, ln = t & 63;
        int c     = ln & 3;
        int srcb  = ln >> 2;
        int pbase = xb * 1024 + wv * 256 + ln;
        #pragma unroll
        for (int k = 0; k < 4; ++k) {
            int src = 16 * k + srcb;       // owner lane of px pbase+k*64 in this wave
            float a0 = __shfl(vx.x, src, 64), a1 = __shfl(vx.y, src, 64),
                  a2 = __shfl(vx.z, src, 64), a3 = __shfl(vx.w, src, 64);
            float b0 = __shfl(vy.x, src, 64), b1 = __shfl(vy.y, src, 64),
                  b2 = __shfl(vy.z, src, 64), b3 = __shfl(vy.w, src, 64);
            float fx00 = (c & 2) ? ((c & 1) ? a3 : a2) : ((c & 1) ? a1 : a0);
            float fy00 = (c & 2) ? ((c & 1) ? b3 : b2) : ((c & 1) ? b1 : b0);
            int p  = pbase + k * 64;
            int yy = p / WW;
            int xx = p - yy * WW;
            float ly  = (float)yy + fy00;
            float lx2 = (float)xx + fx00;
            bool m = (ly >= 0.f) && (ly <= (float)(HH - 1)) &&
                     (lx2 >= 0.f) && (lx2 <= (float)(WW - 1));
            if (m) {
                tm += 1.f;
                float tyf = fminf(fmaxf(floorf(ly),  0.f), (float)(HH - 2));
                float txf = fminf(fmaxf(floorf(lx2), 0.f), (float)(WW - 2));
                float fyy = ly - tyf, fxx = lx2 - txf;
                float gyy = 1.f - fyy, gxx = 1.f - fxx;
                int pix = (int)tyf * WW + (int)txf;
                float sx = gyy * (gxx * gx1[pix]      + fxx * gx1[pix + 1]) +
                           fyy * (gxx * gx1[pix + WW] + fxx * gx1[pix + WW + 1]);
                float sy = gyy * (gxx * gy1[pix]      + fxx * gy1[pix + 1]) +
                           fyy * (gxx * gy1[pix + WW] + fxx * gy1[pix + WW + 1]);
                float dy_ = fy00 - sy;
                float dx_ = fx00 - sx;
                td += fsq(fmaf(dy_, dy_, 1e-9f)) + fsq(fmaf(dx_, dx_, 1e-9f));
            }
        }
    }

    // ---- scatter burst LAST: no vmcnt wait after the atomic ----
    __builtin_amdgcn_sched_barrier(0);       // pin atomic issue after flow loads
    int e = w * EVB + t;
    if (t < EVB && e < BB * NN)
        scatter_one(e, we, pol, tsl, img);
    __builtin_amdgcn_sched_barrier(0);

    waveSum3(acc, td, tm);
    if ((t & 63) == 0) {
        int wid = t >> 6;                    // 0..3
        part[PS + (bp * NXB4 + xb) * 4 + wid] = acc;
        if (j < PP - 1) {
            int bj = b2 * (PP - 1) + j;
            part[PT_D + (bj * NXB4 + xb) * 4 + wid] = td;
            part[PT_M + (bj * NXB4 + xb) * 4 + wid] = tm;
        }
    }
}

// ---------- 2. focus reduction -> partials ----------

__global__ __launch_bounds__(256)
void focus_kernel(const unsigned long long* __restrict__ img,
                  float* __restrict__ part) {
    __shared__ float sm[8];
    int b = blockIdx.y;
    int p = blockIdx.x * 256 + threadIdx.x;
    int y = p / WW;
    int x = p - y * WW;
    unsigned int sp = 0, sn = 0;
    #pragma unroll
    for (int dy = 0; dy < 2; ++dy) {
        #pragma unroll
        for (int dx = 0; dx < 2; ++dx) {
            int ty = y - dy, lx = x - dx;
            if (ty < 0 || lx < 0 || ty > HH - 2 || lx > WW - 2) continue;
            int pi = ((ty & 1) << 1) | (lx & 1);
            size_t base = ((size_t)(pi * BB + b) * 2) * QN + (ty >> 1) * QW + (lx >> 1);
            int sh = 16 * ((dy << 1) | dx);
            sp += (unsigned int)((img[base]      >> sh) & 0xFFFFull);
            sn += (unsigned int)((img[base + QN] >> sh) & 0xFFFFull);
        }
    }
    float tp = (float)sp * INV_SCALE;
    float tn = (float)sn * INV_SCALE;
    float v  = tp * tp + tn * tn;
    float nz = ((sp | sn) != 0u) ? 1.f : 0.f;
    float sv  = blockSum256(v, sm);
    float snz = blockSum256(nz, sm + 4);
    if (threadIdx.x == 0) {
        part[PF_V + b * NXB + blockIdx.x] = sv;
        part[PF_N + b * NXB + blockIdx.x] = snz;
    }
}

// ---------- 3. segment reduce ----------

__global__ __launch_bounds__(256)
void reduce_kernel(const float* __restrict__ part, float* __restrict__ seg) {
    __shared__ float sm[4];
    int s = blockIdx.x;                  // 0..80
    int base, len;
    if (s < 4)       { base = PF_V + s * NXB;             len = NXB; }
    else if (s < 8)  { base = PF_N + (s - 4) * NXB;       len = NXB; }
    else if (s < 44) { base = PT_D + (s - 8) * NXB4 * 4;  len = NXB4 * 4; }
    else if (s < 80) { base = PT_M + (s - 44) * NXB4 * 4; len = NXB4 * 4; }
    else             { base = PS;                         len = BB * PP * NXB4 * 4; }
    float v = 0.f;
    for (int i = threadIdx.x; i < len; i += 256) v += part[base + i];
    float r = blockSum256(v, sm);
    if (threadIdx.x == 0) seg[s] = r;
}

// ---------- 4. final combine ----------

__global__ void final_kernel(const float* __restrict__ seg, float* __restrict__ out) {
    if (threadIdx.x == 0 && blockIdx.x == 0) {
        float focus = 0.f;
        #pragma unroll
        for (int b = 0; b < BB; ++b)
            focus += seg[b] / (seg[BB + b] + 1e-9f);
        float temporal = 0.f;
        #pragma unroll
        for (int k = 0; k < BB * (PP - 1); ++k)
            temporal += seg[8 + k] / (seg[44 + k] + 1e-9f);
        temporal *= 1.0f / (float)(PP - 1);
        out[0] = focus + temporal + seg[80];
    }
}

// ---------- launch ----------

extern "C" void kernel_launch(void* const* d_in, const int* in_sizes, int n_in,
                              void* d_out, int out_size, void* d_ws, size_t ws_size,
                              hipStream_t stream) {
    const float2* we  = (const float2*)d_in[0];  // [B,N,2]
    const float*  pol = (const float*)d_in[1];   // [B,4N,2]
    const float*  tsl = (const float*)d_in[2];   // [B,4N,1]
    const float*  FX  = (const float*)d_in[3];   // [B,P,H,W]
    const float*  FY  = (const float*)d_in[4];   // [B,P,H,W]
    float*              seg  = (float*)d_ws;
    unsigned long long* img  = (unsigned long long*)(seg + 256);   // 8B-aligned
    float*              part = (float*)(img + IMG_QUADS);

    hipMemsetAsync(img, 0, IMG_QUADS * sizeof(unsigned long long), stream);

    fused_kernel<<<NTILE, 256, 0, stream>>>(we, pol, tsl, FX, FY, img, part);
    focus_kernel<<<dim3(NXB, BB), 256, 0, stream>>>(img, part);
    reduce_kernel<<<81, 256, 0, stream>>>(part, seg);
    final_kernel<<<1, 64, 0, stream>>>(seg, (float*)d_out);
}

// Round 12
// 180.292 us; speedup vs baseline: 1.4203x; 1.0019x over previous
//
#include <hip/hip_runtime.h>

#define BB 4
#define PP 10
#define NN 400000
#define HH 480
#define WW 640
constexpr int HW    = HH * WW;        // 307200
constexpr int NXB   = HW / 256;       // 1200 (focus blocks per image)
constexpr int TLW   = 64, TLH = 16;   // 2D flow tile
constexpr int NXT   = (WW / TLW) * (HH / TLH);   // 10*30 = 300 tiles per plane
constexpr int NTILE = NXT * BB * PP;  // 12000
constexpr int CHUNK = NTILE / 8;      // 1500 per XCD
constexpr int EVB   = (BB * NN + NTILE - 1) / NTILE;   // 134 events per block

// gather window: rows [y0-12, y0+28] (41), cols [x0-12, x0+76] (89)
constexpr int WR = 41, WC = 89, WCP = 90;        // padded col stride

// quad images: 4 parity images, each [BB][2][240][320] u64 quads
constexpr int QW = WW / 2, QH = HH / 2, QN = QW * QH;
constexpr size_t IMG_QUADS = (size_t)4 * BB * 2 * QN;   // 19.66 MB

constexpr float SCALE     = 1024.0f;
constexpr float INV_SCALE = 1.0f / 1024.0f;

// ---- partial-sum layout (floats) ----
constexpr int PF_V = 0;                          // [BB][1200]
constexpr int PF_N = PF_V + BB * NXB;
constexpr int PT_D = PF_N + BB * NXB;            // per-wave: [36][300*4]
constexpr int PT_M = PT_D + BB * (PP-1) * NXT * 4;
constexpr int PS   = PT_M + BB * (PP-1) * NXT * 4;    // [40][300*4]
constexpr int NPART = PS + BB * PP * NXT * 4;

// ---------- helpers ----------

__device__ __forceinline__ float fsq(float a) { return __builtin_amdgcn_sqrtf(a); }
__device__ __forceinline__ float charb(float a) { return fsq(fmaf(a, a, 1e-6f)); }

__device__ __forceinline__ void waveSum3(float& a, float& b, float& c) {
    #pragma unroll
    for (int off = 32; off > 0; off >>= 1) {
        a += __shfl_down(a, off, 64);
        b += __shfl_down(b, off, 64);
        c += __shfl_down(c, off, 64);
    }
}

__device__ __forceinline__ float blockSum256(float v, float* smem) {
    #pragma unroll
    for (int off = 32; off > 0; off >>= 1)
        v += __shfl_down(v, off, 64);
    int lane = threadIdx.x & 63;
    int wid  = threadIdx.x >> 6;
    if (lane == 0) smem[wid] = v;
    __syncthreads();
    float r = 0.f;
    if (threadIdx.x == 0) r = smem[0] + smem[1] + smem[2] + smem[3];
    __syncthreads();
    return r;
}

__device__ __forceinline__ void scatter_one(int e,
                                            const float2* __restrict__ we,
                                            const float* __restrict__ pol,
                                            const float* __restrict__ tsl,
                                            unsigned long long* __restrict__ img) {
    int b = e / NN;
    int m = e - b * NN;
    float2 c = we[e];
    float y = c.x, x = c.y;
    float pm0 = pol[((size_t)b * 4 * NN + m) * 2];
    float ts  = tsl[(size_t)b * 4 * NN + m];
    float nts = 1.0f - fabsf(1.0f - ts);
    float tyf = fminf(fmaxf(floorf(y), 0.f), (float)(HH - 2));
    float lxf = fminf(fmaxf(floorf(x), 0.f), (float)(WW - 2));
    float fy_ = y - tyf, fx_ = x - lxf;
    float gy = 1.f - fy_, gx = 1.f - fx_;
    float s = nts * SCALE;
    unsigned long long wTL = (unsigned int)(gy * gx * s + 0.5f);
    unsigned long long wTR = (unsigned int)(gy * fx_ * s + 0.5f);
    unsigned long long wBL = (unsigned int)(fy_ * gx * s + 0.5f);
    unsigned long long wBR = (unsigned int)(fy_ * fx_ * s + 0.5f);
    unsigned long long val = wTL | (wTR << 16) | (wBL << 32) | (wBR << 48);
    int ty = (int)tyf, lx = (int)lxf;
    int pi = ((ty & 1) << 1) | (lx & 1);
    int pl = (pm0 > 0.5f) ? 0 : 1;
    size_t wi = ((size_t)((pi * BB + b) * 2 + pl)) * QN + (ty >> 1) * QW + (lx >> 1);
    atomicAdd(&img[wi], val);
}

// ---------- 1. fused kernel: 2D tiles + LDS-staged temporal gather ----------
// The ~55M scattered L2 sector reads of the temporal gather are replaced by a
// coalesced 29.5KB LDS stage of the (tile + 12px halo) window of plane j+1;
// gathers read LDS. Out-of-window (>4-sigma flow) pixels use the exact global
// fallback. Scatter atomics issue last (never drained by the staging barrier).

__global__ __launch_bounds__(256)
void fused_kernel(const float2* __restrict__ we,
                  const float* __restrict__ pol,
                  const float* __restrict__ tsl,
                  const float* __restrict__ FX, const float* __restrict__ FY,
                  unsigned long long* __restrict__ img,
                  float* __restrict__ part) {
    __shared__ float sfx[WR][WCP];
    __shared__ float sfy[WR][WCP];
    int w = blockIdx.x;
    int t = threadIdx.x;

    // --- tile decode (XCD-chunked bijection) ---
    int l  = (w & 7) * CHUNK + (w >> 3);
    int bp = l / NXT;
    int xb = l - bp * NXT;
    int b2 = bp / PP;
    int j  = bp - b2 * PP;
    int x0 = (xb % (WW / TLW)) * TLW;
    int y0 = (xb / (WW / TLW)) * TLH;
    const float* fx = FX + (size_t)bp * HW;
    const float* fy = FY + (size_t)bp * HW;
    const float* gx1 = fx + HW;
    const float* gy1 = fy + HW;
    bool hasT = (j < PP - 1);

    // ---- stage gather window of plane j+1 into LDS (coalesced) ----
    int wy0 = y0 - 12, wx0 = x0 - 12;
    if (hasT) {
        for (int idx = t; idx < WR * WC; idx += 256) {
            int r = idx / WC, c = idx - r * WC;
            int gy = min(max(wy0 + r, 0), HH - 1);
            int gc = min(max(wx0 + c, 0), WW - 1);
            sfx[r][c] = gx1[gy * WW + gc];
            sfy[r][c] = gy1[gy * WW + gc];
        }
    }

    // ---- spatial phase: thread owns 4 consecutive px of tile row t>>4 ----
    int ypx = y0 + (t >> 4);
    int xpx = x0 + (t & 15) * 4;
    int p0  = ypx * WW + xpx;
    float4 vx = *(const float4*)(fx + p0);
    float4 vy = *(const float4*)(fy + p0);
    bool yin  = (ypx + 1 < HH);
    bool xend = (xpx == WW - 4);
    float4 bx4 = make_float4(0.f, 0.f, 0.f, 0.f), by4 = bx4;
    float vxr = 0.f, vyr = 0.f, bxr = 0.f, byr = 0.f;
    if (yin) {
        bx4 = *(const float4*)(fx + p0 + WW);
        by4 = *(const float4*)(fy + p0 + WW);
    }
    if (!xend) { vxr = fx[p0 + 4]; vyr = fy[p0 + 4]; }
    if (yin && !xend) { bxr = fx[p0 + WW + 4]; byr = fy[p0 + WW + 4]; }

    constexpr float cdx = 1.0f / ((float)HH * (WW - 1) * 4.0f * PP);
    constexpr float cdy = 1.0f / ((float)(HH - 1) * WW * 4.0f * PP);
    constexpr float cdd = 1.0f / ((float)(HH - 1) * (WW - 1) * 4.0f * PP);

    float acc = 0.f;
    acc += (charb(vx.x - vx.y) + charb(vy.x - vy.y)) * cdx;
    acc += (charb(vx.y - vx.z) + charb(vy.y - vy.z)) * cdx;
    acc += (charb(vx.z - vx.w) + charb(vy.z - vy.w)) * cdx;
    if (!xend) acc += (charb(vx.w - vxr) + charb(vy.w - vyr)) * cdx;
    if (yin) {
        acc += (charb(vx.x - bx4.x) + charb(vy.x - by4.x)) * cdy;
        acc += (charb(vx.y - bx4.y) + charb(vy.y - by4.y)) * cdy;
        acc += (charb(vx.z - bx4.z) + charb(vy.z - by4.z)) * cdy;
        acc += (charb(vx.w - bx4.w) + charb(vy.w - by4.w)) * cdy;
        acc += (charb(vx.x - bx4.y) + charb(vy.x - by4.y)) * cdd;
        acc += (charb(vx.y - bx4.z) + charb(vy.y - by4.z)) * cdd;
        acc += (charb(vx.z - bx4.w) + charb(vy.z - by4.w)) * cdd;
        acc += (charb(bx4.x - vx.y) + charb(by4.x - vy.y)) * cdd;
        acc += (charb(bx4.y - vx.z) + charb(by4.y - vy.z)) * cdd;
        acc += (charb(bx4.z - vx.w) + charb(by4.z - vy.w)) * cdd;
        if (!xend) {
            acc += (charb(vx.w - bxr) + charb(vy.w - byr)) * cdd;
            acc += (charb(bx4.w - vxr) + charb(by4.w - vyr)) * cdd;
        }
    }

    // ---- temporal phase: centers already in vx/vy registers; gather via LDS ----
    float td = 0.f, tm = 0.f;
    if (hasT) {
        __syncthreads();                    // staging complete (block-uniform)
        float ax[4] = {vx.x, vx.y, vx.z, vx.w};
        float ay[4] = {vy.x, vy.y, vy.z, vy.w};
        #pragma unroll
        for (int i = 0; i < 4; ++i) {
            float ly  = (float)ypx + ay[i];
            float lx2 = (float)(xpx + i) + ax[i];
            bool m = (ly >= 0.f) && (ly <= (float)(HH - 1)) &&
                     (lx2 >= 0.f) && (lx2 <= (float)(WW - 1));
            if (m) {
                tm += 1.f;
                float tyf = fminf(fmaxf(floorf(ly),  0.f), (float)(HH - 2));
                float txf = fminf(fmaxf(floorf(lx2), 0.f), (float)(WW - 2));
                int ity = (int)tyf, itx = (int)txf;
                float fyy = ly - tyf, fxx = lx2 - txf;
                float gyy = 1.f - fyy, gxx = 1.f - fxx;
                float x00, x01, x10, x11, y00, y01, y10, y11;
                if (ity >= wy0 && ity <= wy0 + WR - 2 &&
                    itx >= wx0 && itx <= wx0 + WC - 2) {
                    int r = ity - wy0, c = itx - wx0;
                    x00 = sfx[r][c];     x01 = sfx[r][c + 1];
                    x10 = sfx[r + 1][c]; x11 = sfx[r + 1][c + 1];
                    y00 = sfy[r][c];     y01 = sfy[r][c + 1];
                    y10 = sfy[r + 1][c]; y11 = sfy[r + 1][c + 1];
                } else {                 // rare >4-sigma displacement: exact fallback
                    int pix = ity * WW + itx;
                    x00 = gx1[pix];      x01 = gx1[pix + 1];
                    x10 = gx1[pix + WW]; x11 = gx1[pix + WW + 1];
                    y00 = gy1[pix];      y01 = gy1[pix + 1];
                    y10 = gy1[pix + WW]; y11 = gy1[pix + WW + 1];
                }
                float sx = gyy * (gxx * x00 + fxx * x01) + fyy * (gxx * x10 + fxx * x11);
                float sy = gyy * (gxx * y00 + fxx * y01) + fyy * (gxx * y10 + fxx * y11);
                float dy_ = ay[i] - sy;
                float dx_ = ax[i] - sx;
                td += fsq(fmaf(dy_, dy_, 1e-9f)) + fsq(fmaf(dx_, dx_, 1e-9f));
            }
        }
    }

    // ---- scatter burst LAST (no vmcnt drain after the atomic) ----
    __builtin_amdgcn_sched_barrier(0);
    int e = w * EVB + t;
    if (t < EVB && e < BB * NN)
        scatter_one(e, we, pol, tsl, img);
    __builtin_amdgcn_sched_barrier(0);

    waveSum3(acc, td, tm);
    if ((t & 63) == 0) {
        int wid = t >> 6;
        part[PS + (bp * NXT + xb) * 4 + wid] = acc;
        if (hasT) {
            int bj = b2 * (PP - 1) + j;
            part[PT_D + (bj * NXT + xb) * 4 + wid] = td;
            part[PT_M + (bj * NXT + xb) * 4 + wid] = tm;
        }
    }
}

// ---------- 2. focus reduction -> partials ----------

__global__ __launch_bounds__(256)
void focus_kernel(const unsigned long long* __restrict__ img,
                  float* __restrict__ part) {
    __shared__ float sm[8];
    int b = blockIdx.y;
    int p = blockIdx.x * 256 + threadIdx.x;
    int y = p / WW;
    int x = p - y * WW;
    unsigned int sp = 0, sn = 0;
    #pragma unroll
    for (int dy = 0; dy < 2; ++dy) {
        #pragma unroll
        for (int dx = 0; dx < 2; ++dx) {
            int ty = y - dy, lx = x - dx;
            if (ty < 0 || lx < 0 || ty > HH - 2 || lx > WW - 2) continue;
            int pi = ((ty & 1) << 1) | (lx & 1);
            size_t base = ((size_t)(pi * BB + b) * 2) * QN + (ty >> 1) * QW + (lx >> 1);
            int sh = 16 * ((dy << 1) | dx);
            sp += (unsigned int)((img[base]      >> sh) & 0xFFFFull);
            sn += (unsigned int)((img[base + QN] >> sh) & 0xFFFFull);
        }
    }
    float tp = (float)sp * INV_SCALE;
    float tn = (float)sn * INV_SCALE;
    float v  = tp * tp + tn * tn;
    float nz = ((sp | sn) != 0u) ? 1.f : 0.f;
    float sv  = blockSum256(v, sm);
    float snz = blockSum256(nz, sm + 4);
    if (threadIdx.x == 0) {
        part[PF_V + b * NXB + blockIdx.x] = sv;
        part[PF_N + b * NXB + blockIdx.x] = snz;
    }
}

// ---------- 3. segment reduce ----------

__global__ __launch_bounds__(256)
void reduce_kernel(const float* __restrict__ part, float* __restrict__ seg) {
    __shared__ float sm[4];
    int s = blockIdx.x;                  // 0..80
    int base, len;
    if (s < 4)       { base = PF_V + s * NXB;            len = NXB; }
    else if (s < 8)  { base = PF_N + (s - 4) * NXB;      len = NXB; }
    else if (s < 44) { base = PT_D + (s - 8) * NXT * 4;  len = NXT * 4; }
    else if (s < 80) { base = PT_M + (s - 44) * NXT * 4; len = NXT * 4; }
    else             { base = PS;                        len = BB * PP * NXT * 4; }
    float v = 0.f;
    for (int i = threadIdx.x; i < len; i += 256) v += part[base + i];
    float r = blockSum256(v, sm);
    if (threadIdx.x == 0) seg[s] = r;
}

// ---------- 4. final combine ----------

__global__ void final_kernel(const float* __restrict__ seg, float* __restrict__ out) {
    if (threadIdx.x == 0 && blockIdx.x == 0) {
        float focus = 0.f;
        #pragma unroll
        for (int b = 0; b < BB; ++b)
            focus += seg[b] / (seg[BB + b] + 1e-9f);
        float temporal = 0.f;
        #pragma unroll
        for (int k = 0; k < BB * (PP - 1); ++k)
            temporal += seg[8 + k] / (seg[44 + k] + 1e-9f);
        temporal *= 1.0f / (float)(PP - 1);
        out[0] = focus + temporal + seg[80];
    }
}

// ---------- launch ----------

extern "C" void kernel_launch(void* const* d_in, const int* in_sizes, int n_in,
                              void* d_out, int out_size, void* d_ws, size_t ws_size,
                              hipStream_t stream) {
    const float2* we  = (const float2*)d_in[0];  // [B,N,2]
    const float*  pol = (const float*)d_in[1];   // [B,4N,2]
    const float*  tsl = (const float*)d_in[2];   // [B,4N,1]
    const float*  FX  = (const float*)d_in[3];   // [B,P,H,W]
    const float*  FY  = (const float*)d_in[4];   // [B,P,H,W]
    float*              seg  = (float*)d_ws;
    unsigned long long* img  = (unsigned long long*)(seg + 256);   // 8B-aligned
    float*              part = (float*)(img + IMG_QUADS);

    hipMemsetAsync(img, 0, IMG_QUADS * sizeof(unsigned long long), stream);

    fused_kernel<<<NTILE, 256, 0, stream>>>(we, pol, tsl, FX, FY, img, part);
    focus_kernel<<<dim3(NXB, BB), 256, 0, stream>>>(img, part);
    reduce_kernel<<<81, 256, 0, stream>>>(part, seg);
    final_kernel<<<1, 64, 0, stream>>>(seg, (float*)d_out);
}

// Round 13
// 171.620 us; speedup vs baseline: 1.4921x; 1.0505x over previous
//
#include <hip/hip_runtime.h>

#define BB 4
#define PP 10
#define NN 400000
#define HH 480
#define WW 640
constexpr int HW    = HH * WW;        // 307200
constexpr int NXB   = HW / 256;       // 1200 (focus blocks per image)
constexpr int TLW   = 64, TLH = 16;   // 2D flow tile
constexpr int NXT   = (WW / TLW) * (HH / TLH);   // 300 tiles per plane
constexpr int NTILE = NXT * BB * PP;  // 12000
constexpr int CHUNK = NTILE / 8;      // 1500 per XCD
constexpr int EVB   = (BB * NN + NTILE - 1) / NTILE;   // 134 events per block

// gather window: rows [y0-10, y0+26] (37), cols [x0-10, x0+74] (85), float2
constexpr int WR = 37, WC = 85;

// quad images: 4 parity images, each [BB][2][240][320] u64 quads
constexpr int QW = WW / 2, QH = HH / 2, QN = QW * QH;
constexpr size_t IMG_QUADS = (size_t)4 * BB * 2 * QN;   // 19.66 MB

constexpr float SCALE     = 1024.0f;
constexpr float INV_SCALE = 1.0f / 1024.0f;

// ---- partial-sum layout (floats) ----
constexpr int PF_V = 0;                          // [BB][1200]
constexpr int PF_N = PF_V + BB * NXB;
constexpr int PT_D = PF_N + BB * NXB;            // per-wave: [36][300*4]
constexpr int PT_M = PT_D + BB * (PP-1) * NXT * 4;
constexpr int PS   = PT_M + BB * (PP-1) * NXT * 4;    // [40][300*4]
constexpr int NPART = PS + BB * PP * NXT * 4;

// ---------- helpers ----------

__device__ __forceinline__ float fsq(float a) { return __builtin_amdgcn_sqrtf(a); }
__device__ __forceinline__ float charb(float a) { return fsq(fmaf(a, a, 1e-6f)); }

__device__ __forceinline__ void waveSum3(float& a, float& b, float& c) {
    #pragma unroll
    for (int off = 32; off > 0; off >>= 1) {
        a += __shfl_down(a, off, 64);
        b += __shfl_down(b, off, 64);
        c += __shfl_down(c, off, 64);
    }
}

__device__ __forceinline__ float blockSum256(float v, float* smem) {
    #pragma unroll
    for (int off = 32; off > 0; off >>= 1)
        v += __shfl_down(v, off, 64);
    int lane = threadIdx.x & 63;
    int wid  = threadIdx.x >> 6;
    if (lane == 0) smem[wid] = v;
    __syncthreads();
    float r = 0.f;
    if (threadIdx.x == 0) r = smem[0] + smem[1] + smem[2] + smem[3];
    __syncthreads();
    return r;
}

// ---------- 1. fused kernel: role-split waves ----------
// Waves 0-3 (256 threads): stage LDS gather window + spatial; after barrier,
//   temporal gather from LDS. Their vmcnt streams NEVER contain an atomic.
// Wave 4 (64 threads): prefetch its 134 events' data to registers BEFORE the
//   barrier (arrives clean), issue all atomics AFTER the barrier, then exit.
//   Its endpgm drain overlaps other blocks' flow compute -> atomic queue is
//   continuously fed instead of per-cohort compute->drain serialization.

__global__ __launch_bounds__(320)
void fused_kernel(const float2* __restrict__ we,
                  const float* __restrict__ pol,
                  const float* __restrict__ tsl,
                  const float* __restrict__ FX, const float* __restrict__ FY,
                  unsigned long long* __restrict__ img,
                  float* __restrict__ part) {
    __shared__ float2 sxy[WR][WC];
    int w = blockIdx.x;
    int t = threadIdx.x;

    // --- tile decode (XCD-chunked bijection) ---
    int l  = (w & 7) * CHUNK + (w >> 3);
    int bp = l / NXT;
    int xb = l - bp * NXT;
    int b2 = bp / PP;
    int j  = bp - b2 * PP;
    int x0 = (xb % (WW / TLW)) * TLW;
    int y0 = (xb / (WW / TLW)) * TLH;
    const float* fx = FX + (size_t)bp * HW;
    const float* fy = FY + (size_t)bp * HW;
    const float* gx1 = fx + HW;
    const float* gy1 = fy + HW;
    bool hasT = (j < PP - 1);
    int wy0 = y0 - 10, wx0 = x0 - 10;

    if (t >= 256) {
        // ================= scatter wave =================
        int ln = t - 256;
        int e0 = w * EVB + ln;
        int e1 = e0 + 64, e2 = e1 + 64;
        bool v0 = (ln      < EVB) && (e0 < BB * NN);
        bool v1 = (ln + 64 < EVB) && (e1 < BB * NN);
        bool v2 = (ln + 128 < EVB) && (e2 < BB * NN);
        float2 c0 = {0,0}, c1 = {0,0}, c2 = {0,0};
        float pm0 = 0, pm1 = 0, pm2 = 0, t0 = 0, t1 = 0, t2 = 0;
        int b0i = 0, b1i = 0, b2i = 0;
        if (v0) { b0i = e0 / NN; int m = e0 - b0i * NN; c0 = we[e0];
                  pm0 = pol[((size_t)b0i * 4 * NN + m) * 2]; t0 = tsl[(size_t)b0i * 4 * NN + m]; }
        if (v1) { b1i = e1 / NN; int m = e1 - b1i * NN; c1 = we[e1];
                  pm1 = pol[((size_t)b1i * 4 * NN + m) * 2]; t1 = tsl[(size_t)b1i * 4 * NN + m]; }
        if (v2) { b2i = e2 / NN; int m = e2 - b2i * NN; c2 = we[e2];
                  pm2 = pol[((size_t)b2i * 4 * NN + m) * 2]; t2 = tsl[(size_t)b2i * 4 * NN + m]; }
        __syncthreads();                 // arrive with only plain loads in flight
        #define DO_SCAT(vv, cc, pm, ts, bi)                                          \
        if (vv) {                                                                    \
            float y = cc.x, x = cc.y;                                                \
            float nts = 1.0f - fabsf(1.0f - (ts));                                   \
            float tyf = fminf(fmaxf(floorf(y), 0.f), (float)(HH - 2));               \
            float lxf = fminf(fmaxf(floorf(x), 0.f), (float)(WW - 2));               \
            float fy_ = y - tyf, fx_ = x - lxf;                                      \
            float gy = 1.f - fy_, gxw = 1.f - fx_;                                   \
            float s = nts * SCALE;                                                   \
            unsigned long long wTL = (unsigned int)(gy * gxw * s + 0.5f);            \
            unsigned long long wTR = (unsigned int)(gy * fx_ * s + 0.5f);            \
            unsigned long long wBL = (unsigned int)(fy_ * gxw * s + 0.5f);           \
            unsigned long long wBR = (unsigned int)(fy_ * fx_ * s + 0.5f);           \
            unsigned long long val = wTL | (wTR << 16) | (wBL << 32) | (wBR << 48);  \
            int ty = (int)tyf, lxq = (int)lxf;                                       \
            int pi = ((ty & 1) << 1) | (lxq & 1);                                    \
            int pl = ((pm) > 0.5f) ? 0 : 1;                                          \
            size_t wi = ((size_t)((pi * BB + (bi)) * 2 + pl)) * QN                   \
                        + (ty >> 1) * QW + (lxq >> 1);                               \
            atomicAdd(&img[wi], val);                                                \
        }
        DO_SCAT(v0, c0, pm0, t0, b0i)
        DO_SCAT(v1, c1, pm1, t1, b1i)
        DO_SCAT(v2, c2, pm2, t2, b2i)
        #undef DO_SCAT
        return;
    }

    // ================= flow waves (t < 256) =================
    // ---- stage gather window of plane j+1 into LDS (coalesced) ----
    if (hasT) {
        for (int idx = t; idx < WR * WC; idx += 256) {
            int r = idx / WC, c = idx - r * WC;
            int gy = min(max(wy0 + r, 0), HH - 1);
            int gc = min(max(wx0 + c, 0), WW - 1);
            int g  = gy * WW + gc;
            sxy[r][c] = make_float2(gx1[g], gy1[g]);
        }
    }

    // ---- spatial phase: thread owns 4 consecutive px of tile row t>>4 ----
    int ypx = y0 + (t >> 4);
    int xpx = x0 + (t & 15) * 4;
    int p0  = ypx * WW + xpx;
    float4 vx = *(const float4*)(fx + p0);
    float4 vy = *(const float4*)(fy + p0);
    bool yin  = (ypx + 1 < HH);
    bool xend = (xpx == WW - 4);
    float4 bx4 = make_float4(0.f, 0.f, 0.f, 0.f), by4 = bx4;
    float vxr = 0.f, vyr = 0.f, bxr = 0.f, byr = 0.f;
    if (yin) {
        bx4 = *(const float4*)(fx + p0 + WW);
        by4 = *(const float4*)(fy + p0 + WW);
    }
    if (!xend) { vxr = fx[p0 + 4]; vyr = fy[p0 + 4]; }
    if (yin && !xend) { bxr = fx[p0 + WW + 4]; byr = fy[p0 + WW + 4]; }

    constexpr float cdx = 1.0f / ((float)HH * (WW - 1) * 4.0f * PP);
    constexpr float cdy = 1.0f / ((float)(HH - 1) * WW * 4.0f * PP);
    constexpr float cdd = 1.0f / ((float)(HH - 1) * (WW - 1) * 4.0f * PP);

    float acc = 0.f;
    acc += (charb(vx.x - vx.y) + charb(vy.x - vy.y)) * cdx;
    acc += (charb(vx.y - vx.z) + charb(vy.y - vy.z)) * cdx;
    acc += (charb(vx.z - vx.w) + charb(vy.z - vy.w)) * cdx;
    if (!xend) acc += (charb(vx.w - vxr) + charb(vy.w - vyr)) * cdx;
    if (yin) {
        acc += (charb(vx.x - bx4.x) + charb(vy.x - by4.x)) * cdy;
        acc += (charb(vx.y - bx4.y) + charb(vy.y - by4.y)) * cdy;
        acc += (charb(vx.z - bx4.z) + charb(vy.z - by4.z)) * cdy;
        acc += (charb(vx.w - bx4.w) + charb(vy.w - by4.w)) * cdy;
        acc += (charb(vx.x - bx4.y) + charb(vy.x - by4.y)) * cdd;
        acc += (charb(vx.y - bx4.z) + charb(vy.y - by4.z)) * cdd;
        acc += (charb(vx.z - bx4.w) + charb(vy.z - by4.w)) * cdd;
        acc += (charb(bx4.x - vx.y) + charb(by4.x - vy.y)) * cdd;
        acc += (charb(bx4.y - vx.z) + charb(by4.y - vy.z)) * cdd;
        acc += (charb(bx4.z - vx.w) + charb(by4.z - vy.w)) * cdd;
        if (!xend) {
            acc += (charb(vx.w - bxr) + charb(vy.w - byr)) * cdd;
            acc += (charb(bx4.w - vxr) + charb(by4.w - vyr)) * cdd;
        }
    }

    __syncthreads();                     // staging visible (no atomics in flight)

    // ---- temporal phase: centers in registers; gather via LDS float2 ----
    float td = 0.f, tm = 0.f;
    if (hasT) {
        float ax[4] = {vx.x, vx.y, vx.z, vx.w};
        float ay[4] = {vy.x, vy.y, vy.z, vy.w};
        #pragma unroll
        for (int i = 0; i < 4; ++i) {
            float ly  = (float)ypx + ay[i];
            float lx2 = (float)(xpx + i) + ax[i];
            bool m = (ly >= 0.f) && (ly <= (float)(HH - 1)) &&
                     (lx2 >= 0.f) && (lx2 <= (float)(WW - 1));
            if (m) {
                tm += 1.f;
                float tyf = fminf(fmaxf(floorf(ly),  0.f), (float)(HH - 2));
                float txf = fminf(fmaxf(floorf(lx2), 0.f), (float)(WW - 2));
                int ity = (int)tyf, itx = (int)txf;
                float fyy = ly - tyf, fxx = lx2 - txf;
                float gyy = 1.f - fyy, gxx = 1.f - fxx;
                float2 q00, q01, q10, q11;
                if (ity >= wy0 && ity <= wy0 + WR - 2 &&
                    itx >= wx0 && itx <= wx0 + WC - 2) {
                    int r = ity - wy0, c = itx - wx0;
                    q00 = sxy[r][c];     q01 = sxy[r][c + 1];
                    q10 = sxy[r + 1][c]; q11 = sxy[r + 1][c + 1];
                } else {                 // >3.3-sigma displacement: exact fallback
                    int pix = ity * WW + itx;
                    q00 = make_float2(gx1[pix],          gy1[pix]);
                    q01 = make_float2(gx1[pix + 1],      gy1[pix + 1]);
                    q10 = make_float2(gx1[pix + WW],     gy1[pix + WW]);
                    q11 = make_float2(gx1[pix + WW + 1], gy1[pix + WW + 1]);
                }
                float sx = gyy * (gxx * q00.x + fxx * q01.x) + fyy * (gxx * q10.x + fxx * q11.x);
                float sy = gyy * (gxx * q00.y + fxx * q01.y) + fyy * (gxx * q10.y + fxx * q11.y);
                float dy_ = ay[i] - sy;
                float dx_ = ax[i] - sx;
                td += fsq(fmaf(dy_, dy_, 1e-9f)) + fsq(fmaf(dx_, dx_, 1e-9f));
            }
        }
    }

    waveSum3(acc, td, tm);
    if ((t & 63) == 0) {
        int wid = t >> 6;
        part[PS + (bp * NXT + xb) * 4 + wid] = acc;
        if (hasT) {
            int bj = b2 * (PP - 1) + j;
            part[PT_D + (bj * NXT + xb) * 4 + wid] = td;
            part[PT_M + (bj * NXT + xb) * 4 + wid] = tm;
        }
    }
}

// ---------- 2. focus reduction -> partials ----------

__global__ __launch_bounds__(256)
void focus_kernel(const unsigned long long* __restrict__ img,
                  float* __restrict__ part) {
    __shared__ float sm[8];
    int b = blockIdx.y;
    int p = blockIdx.x * 256 + threadIdx.x;
    int y = p / WW;
    int x = p - y * WW;
    unsigned int sp = 0, sn = 0;
    #pragma unroll
    for (int dy = 0; dy < 2; ++dy) {
        #pragma unroll
        for (int dx = 0; dx < 2; ++dx) {
            int ty = y - dy, lx = x - dx;
            if (ty < 0 || lx < 0 || ty > HH - 2 || lx > WW - 2) continue;
            int pi = ((ty & 1) << 1) | (lx & 1);
            size_t base = ((size_t)(pi * BB + b) * 2) * QN + (ty >> 1) * QW + (lx >> 1);
            int sh = 16 * ((dy << 1) | dx);
            sp += (unsigned int)((img[base]      >> sh) & 0xFFFFull);
            sn += (unsigned int)((img[base + QN] >> sh) & 0xFFFFull);
        }
    }
    float tp = (float)sp * INV_SCALE;
    float tn = (float)sn * INV_SCALE;
    float v  = tp * tp + tn * tn;
    float nz = ((sp | sn) != 0u) ? 1.f : 0.f;
    float sv  = blockSum256(v, sm);
    float snz = blockSum256(nz, sm + 4);
    if (threadIdx.x == 0) {
        part[PF_V + b * NXB + blockIdx.x] = sv;
        part[PF_N + b * NXB + blockIdx.x] = snz;
    }
}

// ---------- 3. segment reduce ----------

__global__ __launch_bounds__(256)
void reduce_kernel(const float* __restrict__ part, float* __restrict__ seg) {
    __shared__ float sm[4];
    int s = blockIdx.x;                  // 0..80
    int base, len;
    if (s < 4)       { base = PF_V + s * NXB;            len = NXB; }
    else if (s < 8)  { base = PF_N + (s - 4) * NXB;      len = NXB; }
    else if (s < 44) { base = PT_D + (s - 8) * NXT * 4;  len = NXT * 4; }
    else if (s < 80) { base = PT_M + (s - 44) * NXT * 4; len = NXT * 4; }
    else             { base = PS;                        len = BB * PP * NXT * 4; }
    float v = 0.f;
    for (int i = threadIdx.x; i < len; i += 256) v += part[base + i];
    float r = blockSum256(v, sm);
    if (threadIdx.x == 0) seg[s] = r;
}

// ---------- 4. final combine ----------

__global__ void final_kernel(const float* __restrict__ seg, float* __restrict__ out) {
    if (threadIdx.x == 0 && blockIdx.x == 0) {
        float focus = 0.f;
        #pragma unroll
        for (int b = 0; b < BB; ++b)
            focus += seg[b] / (seg[BB + b] + 1e-9f);
        float temporal = 0.f;
        #pragma unroll
        for (int k = 0; k < BB * (PP - 1); ++k)
            temporal += seg[8 + k] / (seg[44 + k] + 1e-9f);
        temporal *= 1.0f / (float)(PP - 1);
        out[0] = focus + temporal + seg[80];
    }
}

// ---------- launch ----------

extern "C" void kernel_launch(void* const* d_in, const int* in_sizes, int n_in,
                              void* d_out, int out_size, void* d_ws, size_t ws_size,
                              hipStream_t stream) {
    const float2* we  = (const float2*)d_in[0];  // [B,N,2]
    const float*  pol = (const float*)d_in[1];   // [B,4N,2]
    const float*  tsl = (const float*)d_in[2];   // [B,4N,1]
    const float*  FX  = (const float*)d_in[3];   // [B,P,H,W]
    const float*  FY  = (const float*)d_in[4];   // [B,P,H,W]
    float*              seg  = (float*)d_ws;
    unsigned long long* img  = (unsigned long long*)(seg + 256);   // 8B-aligned
    float*              part = (float*)(img + IMG_QUADS);

    hipMemsetAsync(img, 0, IMG_QUADS * sizeof(unsigned long long), stream);

    fused_kernel<<<NTILE, 320, 0, stream>>>(we, pol, tsl, FX, FY, img, part);
    focus_kernel<<<dim3(NXB, BB), 256, 0, stream>>>(img, part);
    reduce_kernel<<<81, 256, 0, stream>>>(part, seg);
    final_kernel<<<1, 64, 0, stream>>>(seg, (float*)d_out);
}

// Round 14
// 159.999 us; speedup vs baseline: 1.6004x; 1.0726x over previous
//
#include <hip/hip_runtime.h>

#define BB 4
#define PP 10
#define NN 400000
#define HH 480
#define WW 640
constexpr int HW    = HH * WW;        // 307200
constexpr int NXB   = HW / 256;       // 1200 (focus blocks per image)
constexpr int TLW   = 64, TLH = 16;   // 2D flow tile
constexpr int NXT   = (WW / TLW) * (HH / TLH);   // 300 tiles per plane
constexpr int NTILE = NXT * BB * PP;  // 12000 flow tiles
constexpr int CHUNK = NTILE / 8;      // 1500 per XCD
constexpr int NGRP  = 1000;           // groups of 12 flow + 1 scatter
constexpr int EVS   = BB * NN / NGRP; // 1600 events per scatter block (exact)

// gather window: rows [y0-8, y0+24] (33), cols [x0-8, x0+72] (81), float2
constexpr int WR = 33, WC = 81;       // 21.4 KB LDS -> 7 blocks/CU

// quad images: 4 parity images, each [BB][2][240][320] u64 quads
constexpr int QW = WW / 2, QH = HH / 2, QN = QW * QH;
constexpr size_t IMG_QUADS = (size_t)4 * BB * 2 * QN;   // 19.66 MB

constexpr float SCALE     = 1024.0f;
constexpr float INV_SCALE = 1.0f / 1024.0f;

// ---- partial-sum layout (floats) ----
constexpr int PF_V = 0;                          // [BB][1200]
constexpr int PF_N = PF_V + BB * NXB;
constexpr int PT_D = PF_N + BB * NXB;            // per-wave: [36][300*4]
constexpr int PT_M = PT_D + BB * (PP-1) * NXT * 4;
constexpr int PS   = PT_M + BB * (PP-1) * NXT * 4;    // [40][300*4]
constexpr int NPART = PS + BB * PP * NXT * 4;

// ---------- helpers ----------

__device__ __forceinline__ float fsq(float a) { return __builtin_amdgcn_sqrtf(a); }
__device__ __forceinline__ float charb(float a) { return fsq(fmaf(a, a, 1e-6f)); }

__device__ __forceinline__ void waveSum3(float& a, float& b, float& c) {
    #pragma unroll
    for (int off = 32; off > 0; off >>= 1) {
        a += __shfl_down(a, off, 64);
        b += __shfl_down(b, off, 64);
        c += __shfl_down(c, off, 64);
    }
}

__device__ __forceinline__ float blockSum256(float v, float* smem) {
    #pragma unroll
    for (int off = 32; off > 0; off >>= 1)
        v += __shfl_down(v, off, 64);
    int lane = threadIdx.x & 63;
    int wid  = threadIdx.x >> 6;
    if (lane == 0) smem[wid] = v;
    __syncthreads();
    float r = 0.f;
    if (threadIdx.x == 0) r = smem[0] + smem[1] + smem[2] + smem[3];
    __syncthreads();
    return r;
}

__device__ __forceinline__ void scatter_one(int e,
                                            const float2* __restrict__ we,
                                            const float* __restrict__ pol,
                                            const float* __restrict__ tsl,
                                            unsigned long long* __restrict__ img) {
    int b = e / NN;
    int m = e - b * NN;
    float2 c = we[e];
    float y = c.x, x = c.y;
    float pm0 = pol[((size_t)b * 4 * NN + m) * 2];
    float ts  = tsl[(size_t)b * 4 * NN + m];
    float nts = 1.0f - fabsf(1.0f - ts);
    float tyf = fminf(fmaxf(floorf(y), 0.f), (float)(HH - 2));
    float lxf = fminf(fmaxf(floorf(x), 0.f), (float)(WW - 2));
    float fy_ = y - tyf, fx_ = x - lxf;
    float gy = 1.f - fy_, gx = 1.f - fx_;
    float s = nts * SCALE;
    unsigned long long wTL = (unsigned int)(gy * gx * s + 0.5f);
    unsigned long long wTR = (unsigned int)(gy * fx_ * s + 0.5f);
    unsigned long long wBL = (unsigned int)(fy_ * gx * s + 0.5f);
    unsigned long long wBR = (unsigned int)(fy_ * fx_ * s + 0.5f);
    unsigned long long val = wTL | (wTR << 16) | (wBL << 32) | (wBR << 48);
    int ty = (int)tyf, lx = (int)lxf;
    int pi = ((ty & 1) << 1) | (lx & 1);
    int pl = (pm0 > 0.5f) ? 0 : 1;
    size_t wi = ((size_t)((pi * BB + b) * 2 + pl)) * QN + (ty >> 1) * QW + (lx >> 1);
    atomicAdd(&img[wi], val);
}

// ---------- 1. fused kernel: interleaved block roles ----------
// Groups of 13 blocks: 12 flow blocks (LDS-staged gather, barriers, NO atomics
// anywhere in their instruction stream) + 1 scatter block (1600 events, NO
// barriers; pure atomic firehose). Interleaving keeps ~8% of resident slots
// scattering for the whole kernel -> atomic issue rate ~16G/s, just under the
// ~19G/s drain rate, overlapped with flow compute. 13 and 8 coprime -> scatter
// blocks spread evenly over XCDs.

__global__ __launch_bounds__(256)
void fused_kernel(const float2* __restrict__ we,
                  const float* __restrict__ pol,
                  const float* __restrict__ tsl,
                  const float* __restrict__ FX, const float* __restrict__ FY,
                  unsigned long long* __restrict__ img,
                  float* __restrict__ part) {
    __shared__ float2 sxy[WR][WC];
    int w = blockIdx.x;
    int t = threadIdx.x;
    int group = w / 13;
    int pos   = w - group * 13;

    if (pos == 12) {
        // ================= scatter block =================
        int base = group * EVS;
        for (int k = t; k < EVS; k += 256)
            scatter_one(base + k, we, pol, tsl, img);
        return;
    }

    // ================= flow block =================
    int fidx = group * 12 + pos;
    int l  = (fidx & 7) * CHUNK + (fidx >> 3);   // XCD-chunked bijection
    int bp = l / NXT;
    int xb = l - bp * NXT;
    int b2 = bp / PP;
    int j  = bp - b2 * PP;
    int x0 = (xb % (WW / TLW)) * TLW;
    int y0 = (xb / (WW / TLW)) * TLH;
    const float* fx = FX + (size_t)bp * HW;
    const float* fy = FY + (size_t)bp * HW;
    const float* gx1 = fx + HW;
    const float* gy1 = fy + HW;
    bool hasT = (j < PP - 1);
    int wy0 = y0 - 8, wx0 = x0 - 8;

    // ---- stage gather window of plane j+1 into LDS (coalesced) ----
    if (hasT) {
        for (int idx = t; idx < WR * WC; idx += 256) {
            int r = idx / WC, c = idx - r * WC;
            int gy = min(max(wy0 + r, 0), HH - 1);
            int gc = min(max(wx0 + c, 0), WW - 1);
            int g  = gy * WW + gc;
            sxy[r][c] = make_float2(gx1[g], gy1[g]);
        }
    }

    // ---- spatial phase: thread owns 4 consecutive px of tile row t>>4 ----
    int ypx = y0 + (t >> 4);
    int xpx = x0 + (t & 15) * 4;
    int p0  = ypx * WW + xpx;
    float4 vx = *(const float4*)(fx + p0);
    float4 vy = *(const float4*)(fy + p0);
    bool yin  = (ypx + 1 < HH);
    bool xend = (xpx == WW - 4);
    float4 bx4 = make_float4(0.f, 0.f, 0.f, 0.f), by4 = bx4;
    float vxr = 0.f, vyr = 0.f, bxr = 0.f, byr = 0.f;
    if (yin) {
        bx4 = *(const float4*)(fx + p0 + WW);
        by4 = *(const float4*)(fy + p0 + WW);
    }
    if (!xend) { vxr = fx[p0 + 4]; vyr = fy[p0 + 4]; }
    if (yin && !xend) { bxr = fx[p0 + WW + 4]; byr = fy[p0 + WW + 4]; }

    constexpr float cdx = 1.0f / ((float)HH * (WW - 1) * 4.0f * PP);
    constexpr float cdy = 1.0f / ((float)(HH - 1) * WW * 4.0f * PP);
    constexpr float cdd = 1.0f / ((float)(HH - 1) * (WW - 1) * 4.0f * PP);

    float acc = 0.f;
    acc += (charb(vx.x - vx.y) + charb(vy.x - vy.y)) * cdx;
    acc += (charb(vx.y - vx.z) + charb(vy.y - vy.z)) * cdx;
    acc += (charb(vx.z - vx.w) + charb(vy.z - vy.w)) * cdx;
    if (!xend) acc += (charb(vx.w - vxr) + charb(vy.w - vyr)) * cdx;
    if (yin) {
        acc += (charb(vx.x - bx4.x) + charb(vy.x - by4.x)) * cdy;
        acc += (charb(vx.y - bx4.y) + charb(vy.y - by4.y)) * cdy;
        acc += (charb(vx.z - bx4.z) + charb(vy.z - by4.z)) * cdy;
        acc += (charb(vx.w - bx4.w) + charb(vy.w - by4.w)) * cdy;
        acc += (charb(vx.x - bx4.y) + charb(vy.x - by4.y)) * cdd;
        acc += (charb(vx.y - bx4.z) + charb(vy.y - by4.z)) * cdd;
        acc += (charb(vx.z - bx4.w) + charb(vy.z - by4.w)) * cdd;
        acc += (charb(bx4.x - vx.y) + charb(by4.x - vy.y)) * cdd;
        acc += (charb(bx4.y - vx.z) + charb(by4.y - vy.z)) * cdd;
        acc += (charb(bx4.z - vx.w) + charb(by4.z - vy.w)) * cdd;
        if (!xend) {
            acc += (charb(vx.w - bxr) + charb(vy.w - byr)) * cdd;
            acc += (charb(bx4.w - vxr) + charb(by4.w - vyr)) * cdd;
        }
    }

    __syncthreads();                     // staging visible (no atomics in flight)

    // ---- temporal phase: centers in registers; gather via LDS float2 ----
    float td = 0.f, tm = 0.f;
    if (hasT) {
        float ax[4] = {vx.x, vx.y, vx.z, vx.w};
        float ay[4] = {vy.x, vy.y, vy.z, vy.w};
        #pragma unroll
        for (int i = 0; i < 4; ++i) {
            float ly  = (float)ypx + ay[i];
            float lx2 = (float)(xpx + i) + ax[i];
            bool m = (ly >= 0.f) && (ly <= (float)(HH - 1)) &&
                     (lx2 >= 0.f) && (lx2 <= (float)(WW - 1));
            if (m) {
                tm += 1.f;
                float tyf = fminf(fmaxf(floorf(ly),  0.f), (float)(HH - 2));
                float txf = fminf(fmaxf(floorf(lx2), 0.f), (float)(WW - 2));
                int ity = (int)tyf, itx = (int)txf;
                float fyy = ly - tyf, fxx = lx2 - txf;
                float gyy = 1.f - fyy, gxx = 1.f - fxx;
                float2 q00, q01, q10, q11;
                if (ity >= wy0 && ity <= wy0 + WR - 2 &&
                    itx >= wx0 && itx <= wx0 + WC - 2) {
                    int r = ity - wy0, c = itx - wx0;
                    q00 = sxy[r][c];     q01 = sxy[r][c + 1];
                    q10 = sxy[r + 1][c]; q11 = sxy[r + 1][c + 1];
                } else {                 // rare OOW displacement: exact fallback
                    int pix = ity * WW + itx;
                    q00 = make_float2(gx1[pix],          gy1[pix]);
                    q01 = make_float2(gx1[pix + 1],      gy1[pix + 1]);
                    q10 = make_float2(gx1[pix + WW],     gy1[pix + WW]);
                    q11 = make_float2(gx1[pix + WW + 1], gy1[pix + WW + 1]);
                }
                float sx = gyy * (gxx * q00.x + fxx * q01.x) + fyy * (gxx * q10.x + fxx * q11.x);
                float sy = gyy * (gxx * q00.y + fxx * q01.y) + fyy * (gxx * q10.y + fxx * q11.y);
                float dy_ = ay[i] - sy;
                float dx_ = ax[i] - sx;
                td += fsq(fmaf(dy_, dy_, 1e-9f)) + fsq(fmaf(dx_, dx_, 1e-9f));
            }
        }
    }

    waveSum3(acc, td, tm);
    if ((t & 63) == 0) {
        int wid = t >> 6;
        part[PS + (bp * NXT + xb) * 4 + wid] = acc;
        if (hasT) {
            int bj = b2 * (PP - 1) + j;
            part[PT_D + (bj * NXT + xb) * 4 + wid] = td;
            part[PT_M + (bj * NXT + xb) * 4 + wid] = tm;
        }
    }
}

// ---------- 2. focus reduction -> partials ----------

__global__ __launch_bounds__(256)
void focus_kernel(const unsigned long long* __restrict__ img,
                  float* __restrict__ part) {
    __shared__ float sm[8];
    int b = blockIdx.y;
    int p = blockIdx.x * 256 + threadIdx.x;
    int y = p / WW;
    int x = p - y * WW;
    unsigned int sp = 0, sn = 0;
    #pragma unroll
    for (int dy = 0; dy < 2; ++dy) {
        #pragma unroll
        for (int dx = 0; dx < 2; ++dx) {
            int ty = y - dy, lx = x - dx;
            if (ty < 0 || lx < 0 || ty > HH - 2 || lx > WW - 2) continue;
            int pi = ((ty & 1) << 1) | (lx & 1);
            size_t base = ((size_t)(pi * BB + b) * 2) * QN + (ty >> 1) * QW + (lx >> 1);
            int sh = 16 * ((dy << 1) | dx);
            sp += (unsigned int)((img[base]      >> sh) & 0xFFFFull);
            sn += (unsigned int)((img[base + QN] >> sh) & 0xFFFFull);
        }
    }
    float tp = (float)sp * INV_SCALE;
    float tn = (float)sn * INV_SCALE;
    float v  = tp * tp + tn * tn;
    float nz = ((sp | sn) != 0u) ? 1.f : 0.f;
    float sv  = blockSum256(v, sm);
    float snz = blockSum256(nz, sm + 4);
    if (threadIdx.x == 0) {
        part[PF_V + b * NXB + blockIdx.x] = sv;
        part[PF_N + b * NXB + blockIdx.x] = snz;
    }
}

// ---------- 3. segment reduce ----------

__global__ __launch_bounds__(256)
void reduce_kernel(const float* __restrict__ part, float* __restrict__ seg) {
    __shared__ float sm[4];
    int s = blockIdx.x;                  // 0..80
    int base, len;
    if (s < 4)       { base = PF_V + s * NXB;            len = NXB; }
    else if (s < 8)  { base = PF_N + (s - 4) * NXB;      len = NXB; }
    else if (s < 44) { base = PT_D + (s - 8) * NXT * 4;  len = NXT * 4; }
    else if (s < 80) { base = PT_M + (s - 44) * NXT * 4; len = NXT * 4; }
    else             { base = PS;                        len = BB * PP * NXT * 4; }
    float v = 0.f;
    for (int i = threadIdx.x; i < len; i += 256) v += part[base + i];
    float r = blockSum256(v, sm);
    if (threadIdx.x == 0) seg[s] = r;
}

// ---------- 4. final combine ----------

__global__ void final_kernel(const float* __restrict__ seg, float* __restrict__ out) {
    if (threadIdx.x == 0 && blockIdx.x == 0) {
        float focus = 0.f;
        #pragma unroll
        for (int b = 0; b < BB; ++b)
            focus += seg[b] / (seg[BB + b] + 1e-9f);
        float temporal = 0.f;
        #pragma unroll
        for (int k = 0; k < BB * (PP - 1); ++k)
            temporal += seg[8 + k] / (seg[44 + k] + 1e-9f);
        temporal *= 1.0f / (float)(PP - 1);
        out[0] = focus + temporal + seg[80];
    }
}

// ---------- launch ----------

extern "C" void kernel_launch(void* const* d_in, const int* in_sizes, int n_in,
                              void* d_out, int out_size, void* d_ws, size_t ws_size,
                              hipStream_t stream) {
    const float2* we  = (const float2*)d_in[0];  // [B,N,2]
    const float*  pol = (const float*)d_in[1];   // [B,4N,2]
    const float*  tsl = (const float*)d_in[2];   // [B,4N,1]
    const float*  FX  = (const float*)d_in[3];   // [B,P,H,W]
    const float*  FY  = (const float*)d_in[4];   // [B,P,H,W]
    float*              seg  = (float*)d_ws;
    unsigned long long* img  = (unsigned long long*)(seg + 256);   // 8B-aligned
    float*              part = (float*)(img + IMG_QUADS);

    hipMemsetAsync(img, 0, IMG_QUADS * sizeof(unsigned long long), stream);

    fused_kernel<<<NGRP * 13, 256, 0, stream>>>(we, pol, tsl, FX, FY, img, part);
    focus_kernel<<<dim3(NXB, BB), 256, 0, stream>>>(img, part);
    reduce_kernel<<<81, 256, 0, stream>>>(part, seg);
    final_kernel<<<1, 64, 0, stream>>>(seg, (float*)d_out);
}

// Round 15
// 158.103 us; speedup vs baseline: 1.6196x; 1.0120x over previous
//
#include <hip/hip_runtime.h>

#define BB 4
#define PP 10
#define NN 400000
#define HH 480
#define WW 640
constexpr int HW    = HH * WW;        // 307200
constexpr int NXB   = HW / 256;       // 1200 (focus blocks per image)
constexpr int TLW   = 64, TLH = 16;   // 2D flow tile
constexpr int NXT   = (WW / TLW) * (HH / TLH);   // 300 tiles per plane
constexpr int NTILE = NXT * BB * PP;  // 12000 flow tiles
constexpr int CHUNK = NTILE / 8;      // 1500 per XCD
constexpr int NGRP  = 1000;           // 1000 scatter blocks among 13000 total
constexpr int EVS   = BB * NN / NGRP; // 1600 events per scatter block (exact)

// gather window: rows [y0-8, y0+24] (33), cols [x0-8, x0+72] (81), float2
constexpr int WR = 33, WC = 81;       // 21.4 KB LDS

// quad images: 4 parity images, each [BB][2][240][320] u64 quads
constexpr int QW = WW / 2, QH = HH / 2, QN = QW * QH;
constexpr size_t IMG_QUADS = (size_t)4 * BB * 2 * QN;   // 19.66 MB

constexpr float SCALE     = 1024.0f;
constexpr float INV_SCALE = 1.0f / 1024.0f;

// ---- partial-sum layout (floats) ----
constexpr int PF_V = 0;                          // [BB][1200]
constexpr int PF_N = PF_V + BB * NXB;
constexpr int PT_D = PF_N + BB * NXB;            // per-wave: [36][300*4]
constexpr int PT_M = PT_D + BB * (PP-1) * NXT * 4;
constexpr int PS   = PT_M + BB * (PP-1) * NXT * 4;    // [40][300*4]
constexpr int NPART = PS + BB * PP * NXT * 4;

// ---------- helpers ----------

__device__ __forceinline__ float fsq(float a) { return __builtin_amdgcn_sqrtf(a); }
__device__ __forceinline__ float charb(float a) { return fsq(fmaf(a, a, 1e-6f)); }

__device__ __forceinline__ void waveSum3(float& a, float& b, float& c) {
    #pragma unroll
    for (int off = 32; off > 0; off >>= 1) {
        a += __shfl_down(a, off, 64);
        b += __shfl_down(b, off, 64);
        c += __shfl_down(c, off, 64);
    }
}

__device__ __forceinline__ float blockSum256(float v, float* smem) {
    #pragma unroll
    for (int off = 32; off > 0; off >>= 1)
        v += __shfl_down(v, off, 64);
    int lane = threadIdx.x & 63;
    int wid  = threadIdx.x >> 6;
    if (lane == 0) smem[wid] = v;
    __syncthreads();
    float r = 0.f;
    if (threadIdx.x == 0) r = smem[0] + smem[1] + smem[2] + smem[3];
    __syncthreads();
    return r;
}

__device__ __forceinline__ void scatter_one(int e,
                                            const float2* __restrict__ we,
                                            const float* __restrict__ pol,
                                            const float* __restrict__ tsl,
                                            unsigned long long* __restrict__ img) {
    int b = e / NN;
    int m = e - b * NN;
    float2 c = we[e];
    float y = c.x, x = c.y;
    float pm0 = pol[((size_t)b * 4 * NN + m) * 2];
    float ts  = tsl[(size_t)b * 4 * NN + m];
    float nts = 1.0f - fabsf(1.0f - ts);
    float tyf = fminf(fmaxf(floorf(y), 0.f), (float)(HH - 2));
    float lxf = fminf(fmaxf(floorf(x), 0.f), (float)(WW - 2));
    float fy_ = y - tyf, fx_ = x - lxf;
    float gy = 1.f - fy_, gx = 1.f - fx_;
    float s = nts * SCALE;
    unsigned long long wTL = (unsigned int)(gy * gx * s + 0.5f);
    unsigned long long wTR = (unsigned int)(gy * fx_ * s + 0.5f);
    unsigned long long wBL = (unsigned int)(fy_ * gx * s + 0.5f);
    unsigned long long wBR = (unsigned int)(fy_ * fx_ * s + 0.5f);
    unsigned long long val = wTL | (wTR << 16) | (wBL << 32) | (wBR << 48);
    int ty = (int)tyf, lx = (int)lxf;
    int pi = ((ty & 1) << 1) | (lx & 1);
    int pl = (pm0 > 0.5f) ? 0 : 1;
    size_t wi = ((size_t)((pi * BB + b) * 2 + pl)) * QN + (ty >> 1) * QW + (lx >> 1);
    atomicAdd(&img[wi], val);
}

// ---------- 1. fused kernel: interleaved block roles, XCD-aligned tiles ----------
// Scatter blocks: w % 13 == 12 (1000 of them; no barriers, pure atomics).
// Flow blocks: tile chunk chosen by PHYSICAL residue r = w&7 (XCD round-robin);
// rank = closed-form count of flow blocks < w with the same residue.
// Grid 13000 = 125 periods of lcm(8,13)=104; per period each residue has
// exactly one scatter block (offset 12+13*((5r+4)&7)) and 12 flow blocks.

__global__ __launch_bounds__(256)
void fused_kernel(const float2* __restrict__ we,
                  const float* __restrict__ pol,
                  const float* __restrict__ tsl,
                  const float* __restrict__ FX, const float* __restrict__ FY,
                  unsigned long long* __restrict__ img,
                  float* __restrict__ part) {
    __shared__ float2 sxy[WR][WC];
    int w = blockIdx.x;
    int t = threadIdx.x;

    if (w % 13 == 12) {
        // ================= scatter block =================
        int base = (w / 13) * EVS;
        for (int k = t; k < EVS; k += 256)
            scatter_one(base + k, we, pol, tsl, img);
        return;
    }

    // ================= flow block =================
    int r      = w & 7;
    int period = w / 104;
    int rem    = w - period * 104;
    int sOff   = 12 + 13 * ((5 * r + 4) & 7);          // scatter offset for residue r
    int cnt    = (rem > r) ? (((rem - 1 - r) >> 3) + 1) : 0;
    int rank   = period * 12 + cnt - ((sOff < rem) ? 1 : 0);
    int l      = r * CHUNK + rank;                     // XCD-local contiguous tiles

    int bp = l / NXT;
    int xb = l - bp * NXT;
    int b2 = bp / PP;
    int j  = bp - b2 * PP;
    int x0 = (xb % (WW / TLW)) * TLW;
    int y0 = (xb / (WW / TLW)) * TLH;
    const float* fx = FX + (size_t)bp * HW;
    const float* fy = FY + (size_t)bp * HW;
    const float* gx1 = fx + HW;
    const float* gy1 = fy + HW;
    bool hasT = (j < PP - 1);
    int wy0 = y0 - 8, wx0 = x0 - 8;

    // ---- stage gather window of plane j+1 into LDS (coalesced) ----
    if (hasT) {
        for (int idx = t; idx < WR * WC; idx += 256) {
            int rr = idx / WC, c = idx - rr * WC;
            int gy = min(max(wy0 + rr, 0), HH - 1);
            int gc = min(max(wx0 + c, 0), WW - 1);
            int g  = gy * WW + gc;
            sxy[rr][c] = make_float2(gx1[g], gy1[g]);
        }
    }

    // ---- spatial phase: thread owns 4 consecutive px of tile row t>>4 ----
    int ypx = y0 + (t >> 4);
    int xpx = x0 + (t & 15) * 4;
    int p0  = ypx * WW + xpx;
    float4 vx = *(const float4*)(fx + p0);
    float4 vy = *(const float4*)(fy + p0);
    bool yin  = (ypx + 1 < HH);
    bool xend = (xpx == WW - 4);
    float4 bx4 = make_float4(0.f, 0.f, 0.f, 0.f), by4 = bx4;
    float vxr = 0.f, vyr = 0.f, bxr = 0.f, byr = 0.f;
    if (yin) {
        bx4 = *(const float4*)(fx + p0 + WW);
        by4 = *(const float4*)(fy + p0 + WW);
    }
    if (!xend) { vxr = fx[p0 + 4]; vyr = fy[p0 + 4]; }
    if (yin && !xend) { bxr = fx[p0 + WW + 4]; byr = fy[p0 + WW + 4]; }

    constexpr float cdx = 1.0f / ((float)HH * (WW - 1) * 4.0f * PP);
    constexpr float cdy = 1.0f / ((float)(HH - 1) * WW * 4.0f * PP);
    constexpr float cdd = 1.0f / ((float)(HH - 1) * (WW - 1) * 4.0f * PP);

    float acc = 0.f;
    acc += (charb(vx.x - vx.y) + charb(vy.x - vy.y)) * cdx;
    acc += (charb(vx.y - vx.z) + charb(vy.y - vy.z)) * cdx;
    acc += (charb(vx.z - vx.w) + charb(vy.z - vy.w)) * cdx;
    if (!xend) acc += (charb(vx.w - vxr) + charb(vy.w - vyr)) * cdx;
    if (yin) {
        acc += (charb(vx.x - bx4.x) + charb(vy.x - by4.x)) * cdy;
        acc += (charb(vx.y - bx4.y) + charb(vy.y - by4.y)) * cdy;
        acc += (charb(vx.z - bx4.z) + charb(vy.z - by4.z)) * cdy;
        acc += (charb(vx.w - bx4.w) + charb(vy.w - by4.w)) * cdy;
        acc += (charb(vx.x - bx4.y) + charb(vy.x - by4.y)) * cdd;
        acc += (charb(vx.y - bx4.z) + charb(vy.y - by4.z)) * cdd;
        acc += (charb(vx.z - bx4.w) + charb(vy.z - by4.w)) * cdd;
        acc += (charb(bx4.x - vx.y) + charb(by4.x - vy.y)) * cdd;
        acc += (charb(bx4.y - vx.z) + charb(by4.y - vy.z)) * cdd;
        acc += (charb(bx4.z - vx.w) + charb(by4.z - vy.w)) * cdd;
        if (!xend) {
            acc += (charb(vx.w - bxr) + charb(vy.w - byr)) * cdd;
            acc += (charb(bx4.w - vxr) + charb(by4.w - vyr)) * cdd;
        }
    }

    __syncthreads();                     // staging visible (no atomics in flight)

    // ---- temporal phase: centers in registers; gather via LDS float2 ----
    float td = 0.f, tm = 0.f;
    if (hasT) {
        float ax[4] = {vx.x, vx.y, vx.z, vx.w};
        float ay[4] = {vy.x, vy.y, vy.z, vy.w};
        #pragma unroll
        for (int i = 0; i < 4; ++i) {
            float ly  = (float)ypx + ay[i];
            float lx2 = (float)(xpx + i) + ax[i];
            bool m = (ly >= 0.f) && (ly <= (float)(HH - 1)) &&
                     (lx2 >= 0.f) && (lx2 <= (float)(WW - 1));
            if (m) {
                tm += 1.f;
                float tyf = fminf(fmaxf(floorf(ly),  0.f), (float)(HH - 2));
                float txf = fminf(fmaxf(floorf(lx2), 0.f), (float)(WW - 2));
                int ity = (int)tyf, itx = (int)txf;
                float fyy = ly - tyf, fxx = lx2 - txf;
                float gyy = 1.f - fyy, gxx = 1.f - fxx;
                float2 q00, q01, q10, q11;
                if (ity >= wy0 && ity <= wy0 + WR - 2 &&
                    itx >= wx0 && itx <= wx0 + WC - 2) {
                    int rr = ity - wy0, c = itx - wx0;
                    q00 = sxy[rr][c];     q01 = sxy[rr][c + 1];
                    q10 = sxy[rr + 1][c]; q11 = sxy[rr + 1][c + 1];
                } else {                 // rare OOW displacement: exact fallback
                    int pix = ity * WW + itx;
                    q00 = make_float2(gx1[pix],          gy1[pix]);
                    q01 = make_float2(gx1[pix + 1],      gy1[pix + 1]);
                    q10 = make_float2(gx1[pix + WW],     gy1[pix + WW]);
                    q11 = make_float2(gx1[pix + WW + 1], gy1[pix + WW + 1]);
                }
                float sx = gyy * (gxx * q00.x + fxx * q01.x) + fyy * (gxx * q10.x + fxx * q11.x);
                float sy = gyy * (gxx * q00.y + fxx * q01.y) + fyy * (gxx * q10.y + fxx * q11.y);
                float dy_ = ay[i] - sy;
                float dx_ = ax[i] - sx;
                td += fsq(fmaf(dy_, dy_, 1e-9f)) + fsq(fmaf(dx_, dx_, 1e-9f));
            }
        }
    }

    waveSum3(acc, td, tm);
    if ((t & 63) == 0) {
        int wid = t >> 6;
        part[PS + (bp * NXT + xb) * 4 + wid] = acc;
        if (hasT) {
            int bj = b2 * (PP - 1) + j;
            part[PT_D + (bj * NXT + xb) * 4 + wid] = td;
            part[PT_M + (bj * NXT + xb) * 4 + wid] = tm;
        }
    }
}

// ---------- 2. focus reduction -> partials ----------

__global__ __launch_bounds__(256)
void focus_kernel(const unsigned long long* __restrict__ img,
                  float* __restrict__ part) {
    __shared__ float sm[8];
    int b = blockIdx.y;
    int p = blockIdx.x * 256 + threadIdx.x;
    int y = p / WW;
    int x = p - y * WW;
    unsigned int sp = 0, sn = 0;
    #pragma unroll
    for (int dy = 0; dy < 2; ++dy) {
        #pragma unroll
        for (int dx = 0; dx < 2; ++dx) {
            int ty = y - dy, lx = x - dx;
            if (ty < 0 || lx < 0 || ty > HH - 2 || lx > WW - 2) continue;
            int pi = ((ty & 1) << 1) | (lx & 1);
            size_t base = ((size_t)(pi * BB + b) * 2) * QN + (ty >> 1) * QW + (lx >> 1);
            int sh = 16 * ((dy << 1) | dx);
            sp += (unsigned int)((img[base]      >> sh) & 0xFFFFull);
            sn += (unsigned int)((img[base + QN] >> sh) & 0xFFFFull);
        }
    }
    float tp = (float)sp * INV_SCALE;
    float tn = (float)sn * INV_SCALE;
    float v  = tp * tp + tn * tn;
    float nz = ((sp | sn) != 0u) ? 1.f : 0.f;
    float sv  = blockSum256(v, sm);
    float snz = blockSum256(nz, sm + 4);
    if (threadIdx.x == 0) {
        part[PF_V + b * NXB + blockIdx.x] = sv;
        part[PF_N + b * NXB + blockIdx.x] = snz;
    }
}

// ---------- 3. segment reduce ----------

__global__ __launch_bounds__(256)
void reduce_kernel(const float* __restrict__ part, float* __restrict__ seg) {
    __shared__ float sm[4];
    int s = blockIdx.x;                  // 0..80
    int base, len;
    if (s < 4)       { base = PF_V + s * NXB;            len = NXB; }
    else if (s < 8)  { base = PF_N + (s - 4) * NXB;      len = NXB; }
    else if (s < 44) { base = PT_D + (s - 8) * NXT * 4;  len = NXT * 4; }
    else if (s < 80) { base = PT_M + (s - 44) * NXT * 4; len = NXT * 4; }
    else             { base = PS;                        len = BB * PP * NXT * 4; }
    float v = 0.f;
    for (int i = threadIdx.x; i < len; i += 256) v += part[base + i];
    float r = blockSum256(v, sm);
    if (threadIdx.x == 0) seg[s] = r;
}

// ---------- 4. final combine ----------

__global__ void final_kernel(const float* __restrict__ seg, float* __restrict__ out) {
    if (threadIdx.x == 0 && blockIdx.x == 0) {
        float focus = 0.f;
        #pragma unroll
        for (int b = 0; b < BB; ++b)
            focus += seg[b] / (seg[BB + b] + 1e-9f);
        float temporal = 0.f;
        #pragma unroll
        for (int k = 0; k < BB * (PP - 1); ++k)
            temporal += seg[8 + k] / (seg[44 + k] + 1e-9f);
        temporal *= 1.0f / (float)(PP - 1);
        out[0] = focus + temporal + seg[80];
    }
}

// ---------- launch ----------

extern "C" void kernel_launch(void* const* d_in, const int* in_sizes, int n_in,
                              void* d_out, int out_size, void* d_ws, size_t ws_size,
                              hipStream_t stream) {
    const float2* we  = (const float2*)d_in[0];  // [B,N,2]
    const float*  pol = (const float*)d_in[1];   // [B,4N,2]
    const float*  tsl = (const float*)d_in[2];   // [B,4N,1]
    const float*  FX  = (const float*)d_in[3];   // [B,P,H,W]
    const float*  FY  = (const float*)d_in[4];   // [B,P,H,W]
    float*              seg  = (float*)d_ws;
    unsigned long long* img  = (unsigned long long*)(seg + 256);   // 8B-aligned
    float*              part = (float*)(img + IMG_QUADS);

    hipMemsetAsync(img, 0, IMG_QUADS * sizeof(unsigned long long), stream);

    fused_kernel<<<13000, 256, 0, stream>>>(we, pol, tsl, FX, FY, img, part);
    focus_kernel<<<dim3(NXB, BB), 256, 0, stream>>>(img, part);
    reduce_kernel<<<81, 256, 0, stream>>>(part, seg);
    final_kernel<<<1, 64, 0, stream>>>(seg, (float*)d_out);
}

// Round 16
// 155.306 us; speedup vs baseline: 1.6488x; 1.0180x over previous
//
#include <hip/hip_runtime.h>

#define BB 4
#define PP 10
#define NN 400000
#define HH 480
#define WW 640
constexpr int HW    = HH * WW;        // 307200
constexpr int NXB   = HW / 256;       // 1200 (focus blocks per image)
constexpr int TLW   = 64, TLH = 32;   // 2D flow tile (512 threads, 4 px/thread)
constexpr int NXT   = (WW / TLW) * (HH / TLH);   // 10*15 = 150 tiles per plane
constexpr int NTILE = NXT * BB * PP;  // 6000 flow tiles
constexpr int CHUNK = NTILE / 8;      // 750 per XCD
constexpr int NGRID = 6552;           // 63 periods of lcm(8,13)=104
constexpr int NSC   = 504;            // scatter blocks (pos==12)
constexpr int EVS   = 3175;           // events per scatter block (504*3175 >= 1.6M)

// gather window: rows [y0-8, y0+40] (49), cols [x0-8, x0+72] (81), float2
constexpr int WR = 49, WC = 81;       // 31.75 KB LDS

// quad images: 4 parity images, each [BB][2][240][320] u64 quads
constexpr int QW = WW / 2, QH = HH / 2, QN = QW * QH;
constexpr size_t IMG_QUADS = (size_t)4 * BB * 2 * QN;   // 19.66 MB

constexpr float SCALE     = 1024.0f;
constexpr float INV_SCALE = 1.0f / 1024.0f;

// ---- partial-sum layout (floats); fused tiles write 8 per-wave partials ----
constexpr int PF_V = 0;                          // [BB][1200]
constexpr int PF_N = PF_V + BB * NXB;
constexpr int PT_D = PF_N + BB * NXB;            // [36][150*8]
constexpr int PT_M = PT_D + BB * (PP-1) * NXT * 8;
constexpr int PS   = PT_M + BB * (PP-1) * NXT * 8;    // [40][150*8]
constexpr int NPART = PS + BB * PP * NXT * 8;

// ---------- helpers ----------

__device__ __forceinline__ float fsq(float a) { return __builtin_amdgcn_sqrtf(a); }
__device__ __forceinline__ float charb(float a) { return fsq(fmaf(a, a, 1e-6f)); }

__device__ __forceinline__ void waveSum3(float& a, float& b, float& c) {
    #pragma unroll
    for (int off = 32; off > 0; off >>= 1) {
        a += __shfl_down(a, off, 64);
        b += __shfl_down(b, off, 64);
        c += __shfl_down(c, off, 64);
    }
}

__device__ __forceinline__ float blockSum256(float v, float* smem) {
    #pragma unroll
    for (int off = 32; off > 0; off >>= 1)
        v += __shfl_down(v, off, 64);
    int lane = threadIdx.x & 63;
    int wid  = threadIdx.x >> 6;
    if (lane == 0) smem[wid] = v;
    __syncthreads();
    float r = 0.f;
    if (threadIdx.x == 0) r = smem[0] + smem[1] + smem[2] + smem[3];
    __syncthreads();
    return r;
}

__device__ __forceinline__ void scatter_one(int e,
                                            const float2* __restrict__ we,
                                            const float* __restrict__ pol,
                                            const float* __restrict__ tsl,
                                            unsigned long long* __restrict__ img) {
    int b = e / NN;
    int m = e - b * NN;
    float2 c = we[e];
    float y = c.x, x = c.y;
    float pm0 = pol[((size_t)b * 4 * NN + m) * 2];
    float ts  = tsl[(size_t)b * 4 * NN + m];
    float nts = 1.0f - fabsf(1.0f - ts);
    float tyf = fminf(fmaxf(floorf(y), 0.f), (float)(HH - 2));
    float lxf = fminf(fmaxf(floorf(x), 0.f), (float)(WW - 2));
    float fy_ = y - tyf, fx_ = x - lxf;
    float gy = 1.f - fy_, gx = 1.f - fx_;
    float s = nts * SCALE;
    unsigned long long wTL = (unsigned int)(gy * gx * s + 0.5f);
    unsigned long long wTR = (unsigned int)(gy * fx_ * s + 0.5f);
    unsigned long long wBL = (unsigned int)(fy_ * gx * s + 0.5f);
    unsigned long long wBR = (unsigned int)(fy_ * fx_ * s + 0.5f);
    unsigned long long val = wTL | (wTR << 16) | (wBL << 32) | (wBR << 48);
    int ty = (int)tyf, lx = (int)lxf;
    int pi = ((ty & 1) << 1) | (lx & 1);
    int pl = (pm0 > 0.5f) ? 0 : 1;
    size_t wi = ((size_t)((pi * BB + b) * 2 + pl)) * QN + (ty >> 1) * QW + (lx >> 1);
    atomicAdd(&img[wi], val);
}

// ---------- 1. fused kernel: interleaved roles, 64x32 tiles, XCD-aligned ----------
// Scatter blocks: w % 13 == 12 (504; no barriers, pure atomic firehose).
// Flow blocks: 512 threads, 64x32 tile; chunk chosen by PHYSICAL residue w&7
// (matches XCD round-robin); closed-form rank; rank >= 750 -> idle pad block.

__global__ __launch_bounds__(512)
void fused_kernel(const float2* __restrict__ we,
                  const float* __restrict__ pol,
                  const float* __restrict__ tsl,
                  const float* __restrict__ FX, const float* __restrict__ FY,
                  unsigned long long* __restrict__ img,
                  float* __restrict__ part) {
    __shared__ float2 sxy[WR][WC];
    int w = blockIdx.x;
    int t = threadIdx.x;

    if (w % 13 == 12) {
        // ================= scatter block =================
        int base = (w / 13) * EVS;
        for (int k = t; k < EVS; k += 512) {
            int e = base + k;
            if (e < BB * NN) scatter_one(e, we, pol, tsl, img);
        }
        return;
    }

    // ================= flow block =================
    int r      = w & 7;
    int period = w / 104;
    int rem    = w - period * 104;
    int sOff   = 12 + 13 * ((5 * r + 4) & 7);          // scatter slot for residue r
    int cnt    = (rem > r) ? (((rem - 1 - r) >> 3) + 1) : 0;
    int rank   = period * 12 + cnt - ((sOff < rem) ? 1 : 0);
    if (rank >= CHUNK) return;                         // pad block
    int l      = r * CHUNK + rank;                     // XCD-local contiguous tiles

    int bp = l / NXT;
    int xb = l - bp * NXT;
    int b2 = bp / PP;
    int j  = bp - b2 * PP;
    int x0 = (xb % (WW / TLW)) * TLW;
    int y0 = (xb / (WW / TLW)) * TLH;
    const float* fx = FX + (size_t)bp * HW;
    const float* fy = FY + (size_t)bp * HW;
    const float* gx1 = fx + HW;
    const float* gy1 = fy + HW;
    bool hasT = (j < PP - 1);
    int wy0 = y0 - 8, wx0 = x0 - 8;

    // ---- stage gather window of plane j+1 into LDS (coalesced) ----
    if (hasT) {
        for (int idx = t; idx < WR * WC; idx += 512) {
            int rr = idx / WC, c = idx - rr * WC;
            int gy = min(max(wy0 + rr, 0), HH - 1);
            int gc = min(max(wx0 + c, 0), WW - 1);
            int g  = gy * WW + gc;
            sxy[rr][c] = make_float2(gx1[g], gy1[g]);
        }
    }

    // ---- spatial phase: thread owns 4 consecutive px of tile row t>>4 ----
    int ypx = y0 + (t >> 4);
    int xpx = x0 + (t & 15) * 4;
    int p0  = ypx * WW + xpx;
    float4 vx = *(const float4*)(fx + p0);
    float4 vy = *(const float4*)(fy + p0);
    bool yin  = (ypx + 1 < HH);
    bool xend = (xpx == WW - 4);
    float4 bx4 = make_float4(0.f, 0.f, 0.f, 0.f), by4 = bx4;
    float vxr = 0.f, vyr = 0.f, bxr = 0.f, byr = 0.f;
    if (yin) {
        bx4 = *(const float4*)(fx + p0 + WW);
        by4 = *(const float4*)(fy + p0 + WW);
    }
    if (!xend) { vxr = fx[p0 + 4]; vyr = fy[p0 + 4]; }
    if (yin && !xend) { bxr = fx[p0 + WW + 4]; byr = fy[p0 + WW + 4]; }

    constexpr float cdx = 1.0f / ((float)HH * (WW - 1) * 4.0f * PP);
    constexpr float cdy = 1.0f / ((float)(HH - 1) * WW * 4.0f * PP);
    constexpr float cdd = 1.0f / ((float)(HH - 1) * (WW - 1) * 4.0f * PP);

    float acc = 0.f;
    acc += (charb(vx.x - vx.y) + charb(vy.x - vy.y)) * cdx;
    acc += (charb(vx.y - vx.z) + charb(vy.y - vy.z)) * cdx;
    acc += (charb(vx.z - vx.w) + charb(vy.z - vy.w)) * cdx;
    if (!xend) acc += (charb(vx.w - vxr) + charb(vy.w - vyr)) * cdx;
    if (yin) {
        acc += (charb(vx.x - bx4.x) + charb(vy.x - by4.x)) * cdy;
        acc += (charb(vx.y - bx4.y) + charb(vy.y - by4.y)) * cdy;
        acc += (charb(vx.z - bx4.z) + charb(vy.z - by4.z)) * cdy;
        acc += (charb(vx.w - bx4.w) + charb(vy.w - by4.w)) * cdy;
        acc += (charb(vx.x - bx4.y) + charb(vy.x - by4.y)) * cdd;
        acc += (charb(vx.y - bx4.z) + charb(vy.y - by4.z)) * cdd;
        acc += (charb(vx.z - bx4.w) + charb(vy.z - by4.w)) * cdd;
        acc += (charb(bx4.x - vx.y) + charb(by4.x - vy.y)) * cdd;
        acc += (charb(bx4.y - vx.z) + charb(by4.y - vy.z)) * cdd;
        acc += (charb(bx4.z - vx.w) + charb(by4.z - vy.w)) * cdd;
        if (!xend) {
            acc += (charb(vx.w - bxr) + charb(vy.w - byr)) * cdd;
            acc += (charb(bx4.w - vxr) + charb(by4.w - vyr)) * cdd;
        }
    }

    __syncthreads();                     // staging visible (no atomics in flight)

    // ---- temporal phase: centers in registers; gather via LDS float2 ----
    float td = 0.f, tm = 0.f;
    if (hasT) {
        float ax[4] = {vx.x, vx.y, vx.z, vx.w};
        float ay[4] = {vy.x, vy.y, vy.z, vy.w};
        #pragma unroll
        for (int i = 0; i < 4; ++i) {
            float ly  = (float)ypx + ay[i];
            float lx2 = (float)(xpx + i) + ax[i];
            bool m = (ly >= 0.f) && (ly <= (float)(HH - 1)) &&
                     (lx2 >= 0.f) && (lx2 <= (float)(WW - 1));
            if (m) {
                tm += 1.f;
                float tyf = fminf(fmaxf(floorf(ly),  0.f), (float)(HH - 2));
                float txf = fminf(fmaxf(floorf(lx2), 0.f), (float)(WW - 2));
                int ity = (int)tyf, itx = (int)txf;
                float fyy = ly - tyf, fxx = lx2 - txf;
                float gyy = 1.f - fyy, gxx = 1.f - fxx;
                float2 q00, q01, q10, q11;
                if (ity >= wy0 && ity <= wy0 + WR - 2 &&
                    itx >= wx0 && itx <= wx0 + WC - 2) {
                    int rr = ity - wy0, c = itx - wx0;
                    q00 = sxy[rr][c];     q01 = sxy[rr][c + 1];
                    q10 = sxy[rr + 1][c]; q11 = sxy[rr + 1][c + 1];
                } else {                 // rare OOW displacement: exact fallback
                    int pix = ity * WW + itx;
                    q00 = make_float2(gx1[pix],          gy1[pix]);
                    q01 = make_float2(gx1[pix + 1],      gy1[pix + 1]);
                    q10 = make_float2(gx1[pix + WW],     gy1[pix + WW]);
                    q11 = make_float2(gx1[pix + WW + 1], gy1[pix + WW + 1]);
                }
                float sx = gyy * (gxx * q00.x + fxx * q01.x) + fyy * (gxx * q10.x + fxx * q11.x);
                float sy = gyy * (gxx * q00.y + fxx * q01.y) + fyy * (gxx * q10.y + fxx * q11.y);
                float dy_ = ay[i] - sy;
                float dx_ = ax[i] - sx;
                td += fsq(fmaf(dy_, dy_, 1e-9f)) + fsq(fmaf(dx_, dx_, 1e-9f));
            }
        }
    }

    waveSum3(acc, td, tm);
    if ((t & 63) == 0) {
        int wid = t >> 6;                // 0..7
        part[PS + (bp * NXT + xb) * 8 + wid] = acc;
        if (hasT) {
            int bj = b2 * (PP - 1) + j;
            part[PT_D + (bj * NXT + xb) * 8 + wid] = td;
            part[PT_M + (bj * NXT + xb) * 8 + wid] = tm;
        }
    }
}

// ---------- 2. focus reduction -> partials ----------

__global__ __launch_bounds__(256)
void focus_kernel(const unsigned long long* __restrict__ img,
                  float* __restrict__ part) {
    __shared__ float sm[8];
    int b = blockIdx.y;
    int p = blockIdx.x * 256 + threadIdx.x;
    int y = p / WW;
    int x = p - y * WW;
    unsigned int sp = 0, sn = 0;
    #pragma unroll
    for (int dy = 0; dy < 2; ++dy) {
        #pragma unroll
        for (int dx = 0; dx < 2; ++dx) {
            int ty = y - dy, lx = x - dx;
            if (ty < 0 || lx < 0 || ty > HH - 2 || lx > WW - 2) continue;
            int pi = ((ty & 1) << 1) | (lx & 1);
            size_t base = ((size_t)(pi * BB + b) * 2) * QN + (ty >> 1) * QW + (lx >> 1);
            int sh = 16 * ((dy << 1) | dx);
            sp += (unsigned int)((img[base]      >> sh) & 0xFFFFull);
            sn += (unsigned int)((img[base + QN] >> sh) & 0xFFFFull);
        }
    }
    float tp = (float)sp * INV_SCALE;
    float tn = (float)sn * INV_SCALE;
    float v  = tp * tp + tn * tn;
    float nz = ((sp | sn) != 0u) ? 1.f : 0.f;
    float sv  = blockSum256(v, sm);
    float snz = blockSum256(nz, sm + 4);
    if (threadIdx.x == 0) {
        part[PF_V + b * NXB + blockIdx.x] = sv;
        part[PF_N + b * NXB + blockIdx.x] = snz;
    }
}

// ---------- 3. segment reduce ----------

__global__ __launch_bounds__(256)
void reduce_kernel(const float* __restrict__ part, float* __restrict__ seg) {
    __shared__ float sm[4];
    int s = blockIdx.x;                  // 0..80
    int base, len;
    if (s < 4)       { base = PF_V + s * NXB;            len = NXB; }
    else if (s < 8)  { base = PF_N + (s - 4) * NXB;      len = NXB; }
    else if (s < 44) { base = PT_D + (s - 8) * NXT * 8;  len = NXT * 8; }
    else if (s < 80) { base = PT_M + (s - 44) * NXT * 8; len = NXT * 8; }
    else             { base = PS;                        len = BB * PP * NXT * 8; }
    float v = 0.f;
    for (int i = threadIdx.x; i < len; i += 256) v += part[base + i];
    float r = blockSum256(v, sm);
    if (threadIdx.x == 0) seg[s] = r;
}

// ---------- 4. final combine ----------

__global__ void final_kernel(const float* __restrict__ seg, float* __restrict__ out) {
    if (threadIdx.x == 0 && blockIdx.x == 0) {
        float focus = 0.f;
        #pragma unroll
        for (int b = 0; b < BB; ++b)
            focus += seg[b] / (seg[BB + b] + 1e-9f);
        float temporal = 0.f;
        #pragma unroll
        for (int k = 0; k < BB * (PP - 1); ++k)
            temporal += seg[8 + k] / (seg[44 + k] + 1e-9f);
        temporal *= 1.0f / (float)(PP - 1);
        out[0] = focus + temporal + seg[80];
    }
}

// ---------- launch ----------

extern "C" void kernel_launch(void* const* d_in, const int* in_sizes, int n_in,
                              void* d_out, int out_size, void* d_ws, size_t ws_size,
                              hipStream_t stream) {
    const float2* we  = (const float2*)d_in[0];  // [B,N,2]
    const float*  pol = (const float*)d_in[1];   // [B,4N,2]
    const float*  tsl = (const float*)d_in[2];   // [B,4N,1]
    const float*  FX  = (const float*)d_in[3];   // [B,P,H,W]
    const float*  FY  = (const float*)d_in[4];   // [B,P,H,W]
    float*              seg  = (float*)d_ws;
    unsigned long long* img  = (unsigned long long*)(seg + 256);   // 8B-aligned
    float*              part = (float*)(img + IMG_QUADS);

    hipMemsetAsync(img, 0, IMG_QUADS * sizeof(unsigned long long), stream);

    fused_kernel<<<NGRID, 512, 0, stream>>>(we, pol, tsl, FX, FY, img, part);
    focus_kernel<<<dim3(NXB, BB), 256, 0, stream>>>(img, part);
    reduce_kernel<<<81, 256, 0, stream>>>(part, seg);
    final_kernel<<<1, 64, 0, stream>>>(seg, (float*)d_out);
}